// Round 14
// baseline (21696.860 us; speedup 1.0000x reference)
//
#include <hip/hip_runtime.h>
#include <stdint.h>
#include <math.h>

// ====================== problem constants ======================
#define NNODE 256
#define BATCH 32
#define TLEN  128
#define ROWS  8192 // NNODE*BATCH

typedef unsigned short u16;
typedef short bf16x8 __attribute__((ext_vector_type(8)));
typedef float f32x4 __attribute__((ext_vector_type(4)));

__device__ inline u16 f2bf_rn(float v) {
  uint32_t u = __float_as_uint(v);
  u += 0x7fffu + ((u >> 16) & 1u);
  return (u16)(u >> 16);
}
__device__ inline float bf2f(u16 h) { return __uint_as_float(((uint32_t)h) << 16); }
__device__ inline void split2(float v, u16& hi, u16& lo) {
  hi = f2bf_rn(v);
  lo = f2bf_rn(v - bf2f(hi));
}

// packed-state element address: fragment (ct=c/16, b, mc=n/32), lane-major
__device__ inline size_t pk_addr(int c, int b, int n) {
  return ((((size_t)(c >> 4) * 32 + b) * 8 + (n >> 5)) << 9) +
         (((size_t)((c & 15) | (((n >> 3) & 3) << 4))) << 3) + (n & 7);
}

// coherent 16B load (bypasses stale L1) — for fresh cross-block data
__device__ __forceinline__ bf16x8 load16_sc0(const u16* p) {
  bf16x8 r;
  asm volatile("global_load_dwordx4 %0, %1, off sc0" : "=v"(r) : "v"(p));
  return r;
}

// ====================== Threefry-2x32 (20 rounds) ======================
__host__ __device__ inline uint32_t rotl32_(uint32_t v, int d) {
  return (v << d) | (v >> (32 - d));
}
__host__ __device__ inline void tf2x32(uint32_t k0, uint32_t k1, uint32_t x0,
                                       uint32_t x1, uint32_t* o0, uint32_t* o1) {
  uint32_t ks2 = k0 ^ k1 ^ 0x1BD11BDAu;
  x0 += k0; x1 += k1;
  x0 += x1; x1 = rotl32_(x1, 13); x1 ^= x0;
  x0 += x1; x1 = rotl32_(x1, 15); x1 ^= x0;
  x0 += x1; x1 = rotl32_(x1, 26); x1 ^= x0;
  x0 += x1; x1 = rotl32_(x1, 6);  x1 ^= x0;
  x0 += k1; x1 += ks2 + 1u;
  x0 += x1; x1 = rotl32_(x1, 17); x1 ^= x0;
  x0 += x1; x1 = rotl32_(x1, 29); x1 ^= x0;
  x0 += x1; x1 = rotl32_(x1, 16); x1 ^= x0;
  x0 += x1; x1 = rotl32_(x1, 24); x1 ^= x0;
  x0 += ks2; x1 += k0 + 2u;
  x0 += x1; x1 = rotl32_(x1, 13); x1 ^= x0;
  x0 += x1; x1 = rotl32_(x1, 15); x1 ^= x0;
  x0 += x1; x1 = rotl32_(x1, 26); x1 ^= x0;
  x0 += x1; x1 = rotl32_(x1, 6);  x1 ^= x0;
  x0 += k0; x1 += k1 + 3u;
  x0 += x1; x1 = rotl32_(x1, 17); x1 ^= x0;
  x0 += x1; x1 = rotl32_(x1, 29); x1 ^= x0;
  x0 += x1; x1 = rotl32_(x1, 16); x1 ^= x0;
  x0 += x1; x1 = rotl32_(x1, 24); x1 ^= x0;
  x0 += k1; x1 += ks2 + 4u;
  x0 += x1; x1 = rotl32_(x1, 13); x1 ^= x0;
  x0 += x1; x1 = rotl32_(x1, 15); x1 ^= x0;
  x0 += x1; x1 = rotl32_(x1, 26); x1 ^= x0;
  x0 += x1; x1 = rotl32_(x1, 6);  x1 ^= x0;
  x0 += ks2; x1 += k0 + 5u;
  *o0 = x0; *o1 = x1;
}

__device__ inline float gumbel_at(uint32_t k0, uint32_t k1, uint32_t idx) {
  uint32_t o0, o1;
  tf2x32(k0, k1, 0u, idx, &o0, &o1);
  uint32_t b = o0 ^ o1;
  float f = __uint_as_float((b >> 9) | 0x3f800000u) - 1.0f;
  const float tiny = 1.17549435e-38f;
  float u = fmaxf(tiny, f + tiny);
  return -logf(-logf(u));
}

// ====================== graph setup kernels (fp32, one-time) ======================
__global__ __launch_bounds__(256) void setup_embed_kernel(
    const float* __restrict__ We1, const float* __restrict__ We2,
    const float* __restrict__ Mem, float* __restrict__ e1, float* __restrict__ e2,
    float* __restrict__ n1, float* __restrict__ n2) {
  int n = threadIdx.x;
  float a[8];
  float s;
  for (int m = 0; m < 8; ++m) a[m] = We1[n * 8 + m];
  s = 0.f;
  for (int j = 0; j < 32; ++j) {
    float v = 0.f;
    for (int m = 0; m < 8; ++m) v = fmaf(a[m], Mem[m * 32 + j], v);
    e1[n * 32 + j] = v;
    s = fmaf(v, v, s);
  }
  n1[n] = sqrtf(s);
  for (int m = 0; m < 8; ++m) a[m] = We2[n * 8 + m];
  s = 0.f;
  for (int j = 0; j < 32; ++j) {
    float v = 0.f;
    for (int m = 0; m < 8; ++m) v = fmaf(a[m], Mem[m * 32 + j], v);
    e2[n * 32 + j] = v;
    s = fmaf(v, v, s);
  }
  n2[n] = sqrtf(s);
}

__global__ void stats_init_kernel(int* stats) {
  stats[0] = 0;
  stats[1] = 0;
  stats[2] = 0x7fffffff;
}

__global__ __launch_bounds__(256) void adj_kernel(
    const float* __restrict__ eA, const float* __restrict__ eB,
    const float* __restrict__ nA, const float* __restrict__ nB,
    uint32_t k0, uint32_t k1, float* __restrict__ adj, float* __restrict__ deg,
    int* __restrict__ stats) {
  int i = blockIdx.x, j = threadIdx.x;
  float dot = 0.f;
  for (int c = 0; c < 32; ++c) dot = fmaf(eA[i * 32 + c], eB[j * 32 + c], dot);
  float g = dot / (nA[i] * nB[j] + 1e-6f);
  g = (g + 1.0f) * 0.5f;
  uint32_t f = ((uint32_t)(i * 256 + j)) * 2u;
  float g0 = gumbel_at(k0, k1, f);
  float g1 = gumbel_at(k0, k1, f + 1u);
  float a = ((g + g0) >= ((1.0f - g) + g1)) ? 1.0f : 0.0f;
  if (i == j) a = 0.0f;
  adj[i * 256 + j] = a;
  __shared__ float red[256];
  red[j] = a;
  __syncthreads();
  for (int s = 128; s > 0; s >>= 1) {
    if (j < s) red[j] += red[j + s];
    __syncthreads();
  }
  if (j == 0) {
    float d = red[0];
    deg[i] = d;
    atomicMax(&stats[0], (int)d);
    atomicMin(&stats[2], (int)d);
    if (d > 0.5f) atomicOr(&stats[1], 1);
  }
}

__global__ __launch_bounds__(256) void lap_kernel(const float* __restrict__ adj,
                                                  const float* __restrict__ deg,
                                                  const int* __restrict__ stats,
                                                  float* __restrict__ S1) {
  int i = blockIdx.x, j = threadIdx.x;
  float lmax = (float)stats[0];
  float lmin = stats[1] ? -1.0f : (float)stats[2];
  float lam = lmax - lmin;
  float L = (i == j) ? deg[i] : -adj[i * 256 + j];
  S1[i * 256 + j] = 2.0f * L / lam - ((i == j) ? 1.0f : 0.0f);
}

// T2 = 2*(S1@S1) - I  (fp32 VALU tile GEMM, one-time)
__global__ __launch_bounds__(256) void t2_kernel(const float* __restrict__ A,
                                                 float* __restrict__ Cout) {
  __shared__ __align__(16) float sAT[32][68];
  __shared__ __align__(16) float sB[32][68];
  int tid = threadIdx.x;
  int tc = tid & 15, tr = tid >> 4;
  int row0 = blockIdx.y * 64, col0 = blockIdx.x * 64;
  float acc[4][4] = {};
  for (int m0 = 0; m0 < 256; m0 += 32) {
    for (int i = tid; i < 2048; i += 256) {
      int r = i >> 5, c = i & 31;
      sAT[c][r] = A[(size_t)(row0 + r) * 256 + m0 + c];
    }
    for (int i = tid; i < 2048; i += 256) {
      int r = i >> 6, c = i & 63;
      sB[r][c] = A[(size_t)(m0 + r) * 256 + col0 + c];
    }
    __syncthreads();
#pragma unroll
    for (int kk = 0; kk < 32; ++kk) {
      float4 av = *(const float4*)&sAT[kk][tr * 4];
      float4 bv = *(const float4*)&sB[kk][tc * 4];
      float a[4] = {av.x, av.y, av.z, av.w};
      float b[4] = {bv.x, bv.y, bv.z, bv.w};
#pragma unroll
      for (int i = 0; i < 4; ++i)
#pragma unroll
        for (int j = 0; j < 4; ++j) acc[i][j] = fmaf(a[i], b[j], acc[i][j]);
    }
    __syncthreads();
  }
#pragma unroll
  for (int i = 0; i < 4; ++i) {
    int row = row0 + tr * 4 + i;
#pragma unroll
    for (int j = 0; j < 4; ++j) {
      int col = col0 + tc * 4 + j;
      Cout[(size_t)row * 256 + col] = 2.0f * acc[i][j] - ((row == col) ? 1.0f : 0.0f);
    }
  }
}

// S fp32 -> fragment-packed hi/lo bf16
__global__ void cvt_s_packed(const float* __restrict__ S, u16* __restrict__ Sh,
                             u16* __restrict__ Sl) {
  int idx = blockIdx.x * 256 + threadIdx.x;
  if (idx >= 4 * 65536) return;
  int p = idx >> 16, rem = idx & 65535;
  int n = rem >> 8, m = rem & 255;
  int nt = n >> 4, li = n & 15;
  int mc = m >> 5, g = (m >> 3) & 3, j = m & 7;
  int lane = li | (g << 4);
  size_t a = (((size_t)(p * 16 + nt) * 8 + mc) << 9) + lane * 8 + j;
  u16 h, l;
  split2(S[idx], h, l);
  Sh[a] = h; Sl[a] = l;
}

// W fragment-packed (k=3 folded into p=0; c==0/c==hid via rank-1 w0/wlast)
__global__ void build_wfrag(const float* __restrict__ W, int C, int O, int hid,
                            u16* __restrict__ WfH, u16* __restrict__ WfL,
                            float* __restrict__ w0, float* __restrict__ wlast) {
  int idx = blockIdx.x * 256 + threadIdx.x;
  int nKC = hid / 32;
  if (idx < 5 * hid * O) {
    int kk = idx & 31;
    int rest = idx >> 5;
    int o = rest % O; rest /= O;
    int kc = rest % nKC;
    int p = rest / nKC;
    int korig = (p == 0) ? 0 : (p + (p >= 3 ? 1 : 0));
    int c = kc * 32 + kk;
    float v = 0.f;
    if (c > 0) {
      v = W[(size_t)(korig * C + c) * O + o];
      if (p == 0) v += W[(size_t)(3 * C + c) * O + o];
    }
    int ot = o >> 4, li = o & 15, g = kk >> 3, j = kk & 7;
    int lane = li | (g << 4);
    size_t a = (((size_t)(p * nKC + kc) * (O / 16) + ot) << 9) + lane * 8 + j;
    u16 h, l; split2(v, h, l);
    WfH[a] = h; WfL[a] = l;
  }
  if (idx < 5 * O) {
    int o = idx % O, p = idx / O;
    int korig = (p == 0) ? 0 : (p + (p >= 3 ? 1 : 0));
    float v0 = W[(size_t)(korig * C + 0) * O + o];
    if (p == 0) v0 += W[(size_t)(3 * C + 0) * O + o];
    w0[p * O + o] = v0;
    float vl = W[(size_t)(korig * C + hid) * O + o];
    if (p == 0) vl += W[(size_t)(3 * C + hid) * O + o];
    wlast[p * O + o] = vl;
  }
}

__global__ void zero_kernel(uint4* __restrict__ p, int n4) {
  for (int i = blockIdx.x * blockDim.x + threadIdx.x; i < n4;
       i += gridDim.x * blockDim.x)
    p[i] = make_uint4(0, 0, 0, 0);
}

// encoder state init: packed ch0 = x[:,0] (rest already zeroed)
__global__ void enc_init(const float* __restrict__ x,
                         u16* __restrict__ pkh, u16* __restrict__ pkl) {
  int col = blockIdx.x * 256 + threadIdx.x;
  if (col >= ROWS) return;
  int b = col >> 8, n = col & 255;
  float v = x[(size_t)b * (TLEN * NNODE) + n];
  u16 h, l; split2(v, h, l);
  size_t a = pk_addr(0, b, n);
  pkh[a] = h; pkl[a] = l;
}

// attention + decoder state init (packed only)
__global__ __launch_bounds__(128) void attn2(const u16* __restrict__ hEh,
                                             const u16* __restrict__ hEl,
                                             const float* __restrict__ Wq,
                                             const float* __restrict__ Mem,
                                             u16* __restrict__ pkh,
                                             u16* __restrict__ pkl) {
  int col = blockIdx.x * 128 + threadIdx.x;
  int b = col >> 8, n = col & 255;
  float h[64];
  for (int c = 0; c < 64; ++c) {
    size_t a = pk_addr(1 + c, b, n);
    h[c] = bf2f(hEh[a]) + bf2f(hEl[a]);
  }
  float q[32];
  for (int j = 0; j < 32; ++j) {
    float s = 0.f;
    for (int c = 0; c < 64; ++c) s = fmaf(h[c], Wq[c * 32 + j], s);
    q[j] = s;
  }
  float l[8], mx = -3.402823466e38f;
  for (int m = 0; m < 8; ++m) {
    float s = 0.f;
    for (int j = 0; j < 32; ++j) s = fmaf(q[j], Mem[m * 32 + j], s);
    l[m] = s;
    mx = fmaxf(mx, s);
  }
  float se = 0.f;
  for (int m = 0; m < 8; ++m) { l[m] = expf(l[m] - mx); se += l[m]; }
  float val[32];
  for (int j = 0; j < 32; ++j) {
    float v = 0.f;
    for (int m = 0; m < 8; ++m) v = fmaf(l[m] / se, Mem[m * 32 + j], v);
    val[j] = v;
  }
  for (int c = 0; c < 97; ++c) {
    float v = (c == 0) ? 0.f : ((c <= 64) ? h[c - 1] : val[c - 65]);
    u16 hh, ll; split2(v, hh, ll);
    size_t a = pk_addr(c, b, n);
    pkh[a] = hh; pkl[a] = ll;
  }
}

// ====================== half-step device function ======================
// R13 body, with A-fragments staged ONCE per block via sc0->VGPR->LDS in two
// 4-chunk rounds (cross-block fresh data; sc0 bypasses stale L1).
// S/W/own-column state use plain loads (read-only or own-block round-trip).
template <int C, int HID, int O, int NKC, int MT1, int MODE>
__device__ __forceinline__ void half_step(
    const u16* ApkH, const u16* ApkL,
    const u16* SpkH, const u16* SpkL,
    const u16* WpkH, const u16* WpkL,
    const float* w0, const float* wlast, const float* bias,
    const u16* stH, const u16* stL,
    u16* outPkH, u16* outPkL,
    float* rbuf, const float* xsrc, int tnext,
    const float* pw, const float* pb, float* outp, int tcur,
    u16* GhR, u16* GlR, u16* stg) {
  constexpr int MT2 = O / 16;
  constexpr int MT1A = (MT1 + 1) / 2;
  constexpr int CH0SLOT = HID + 1;
  constexpr int KS8 = (HID + 9) / 8;
  constexpr int NFR = MT1 * 8;            // frags per round: 4 chunks x MT1 x 2
  constexpr int KTRIP = (NFR + 15) / 16;

  float* projL = (float*)stg;  // aliased; used in MODE 2 tail only

  auto Gidx = [](int c2, int p, int li, int slot) -> size_t {
    return (((size_t)((c2 * 5 + p) * KS8 + (slot >> 3)) * 16 + li) << 3) +
           (slot & 7);
  };

  const int tid = threadIdx.x;
  const int wid = tid >> 6, lane = tid & 63;
  const int g = lane >> 4, li = lane & 15;
  const int cgi = wid >> 3, pp = wid & 3, half = (wid >> 2) & 1;
  const int bid0 = (int)blockIdx.x;
  const int bidx = ((bid0 & 7) << 5) | (bid0 >> 3);
  const int col0 = bidx * 32;
  const int b = col0 >> 8;
  const int nb = col0 & 255;
  const int n0 = nb + cgi * 16;
  const int nt = n0 >> 4;

  f32x4 acc1[MT1A];
#pragma unroll
  for (int i = 0; i < MT1A; ++i) acc1[i] = (f32x4){0.f, 0.f, 0.f, 0.f};

  // ---- stage + compute GEMM1 in two 4-chunk rounds ----
#pragma unroll
  for (int r = 0; r < 2; ++r) {
    // issue this wave's share of sc0 A-fragment loads
    bf16x8 areg[KTRIP];
#pragma unroll
    for (int k = 0; k < KTRIP; ++k) {
      int f = wid + k * 16;
      if (f < NFR) {
        int hl = f & 1, rest = f >> 1;
        int mt = rest % MT1, mcl = rest / MT1;
        int mc = r * 4 + mcl;
        const u16* src = (hl ? ApkL : ApkH) +
                         ((((size_t)(mt * 32 + b) * 8 + mc) << 9) + lane * 8);
        areg[k] = load16_sc0(src);
      }
    }
    if (r == 0) {
      // G_0 copy (own-block packed state, plain) — overlaps sc0 latency
      for (int i = tid; i < 32 * C; i += 1024) {
        int c = i >> 5, q = i & 31;
        size_t a = pk_addr(c, b, nb + q);
        int slot = (c == 0) ? CH0SLOT : c;
        GhR[Gidx(q >> 4, 0, q & 15, slot)] = ApkH[a];
        GlR[Gidx(q >> 4, 0, q & 15, slot)] = ApkL[a];
      }
      if (tid < 32) {
        GhR[Gidx(tid >> 4, 0, tid & 15, 0)] = 0;
        GlR[Gidx(tid >> 4, 0, tid & 15, 0)] = 0;
      }
    }
    asm volatile("s_waitcnt vmcnt(0)" ::: "memory");
#pragma unroll
    for (int k = 0; k < KTRIP; ++k) {
      int f = wid + k * 16;
      if (f < NFR) *(bf16x8*)&stg[(size_t)f * 512 + lane * 8] = areg[k];
    }
    __syncthreads();
    // compute chunks r*4 .. r*4+3 from staged A + plain S
#pragma unroll
    for (int mcl = 0; mcl < 4; ++mcl) {
      int mc = r * 4 + mcl;
      size_t sa = (((size_t)(pp * 16 + nt) * 8 + mc) << 9) + lane * 8;
      bf16x8 sbh = *(const bf16x8*)(SpkH + sa);
      bf16x8 sbl = *(const bf16x8*)(SpkL + sa);
#pragma unroll
      for (int i = 0; i < MT1A; ++i) {
        const int mt = half * MT1A + i;
        if (mt < MT1) {
          const size_t fb = (size_t)((mcl * MT1 + mt) * 2) * 512 + lane * 8;
          bf16x8 ah = *(const bf16x8*)&stg[fb];
          bf16x8 al = *(const bf16x8*)&stg[fb + 512];
          acc1[i] = __builtin_amdgcn_mfma_f32_16x16x32_bf16(ah, sbh, acc1[i], 0, 0, 0);
          acc1[i] = __builtin_amdgcn_mfma_f32_16x16x32_bf16(ah, sbl, acc1[i], 0, 0, 0);
          acc1[i] = __builtin_amdgcn_mfma_f32_16x16x32_bf16(al, sbh, acc1[i], 0, 0, 0);
        }
      }
    }
    __syncthreads();  // all stg reads done before next round's overwrite
  }

  // ---- epi1: split + write G_{pp+1} to LDS ----
  {
    const int p = pp + 1;
#pragma unroll
    for (int i = 0; i < MT1A; ++i) {
      const int mt = half * MT1A + i;
      if (mt < MT1) {
        int cq = mt * 16 + 4 * g;
        u16 h4[4], l4[4];
#pragma unroll
        for (int r = 0; r < 4; ++r) split2(acc1[i][r], h4[r], l4[r]);
        if (cq == 0) {
          GhR[Gidx(cgi, p, li, CH0SLOT)] = h4[0];
          GlR[Gidx(cgi, p, li, CH0SLOT)] = l4[0];
          h4[0] = 0; l4[0] = 0;
        }
        if (cq + 3 <= HID) {
          uint2 vh, vl;
          vh.x = (uint32_t)h4[0] | ((uint32_t)h4[1] << 16);
          vh.y = (uint32_t)h4[2] | ((uint32_t)h4[3] << 16);
          vl.x = (uint32_t)l4[0] | ((uint32_t)l4[1] << 16);
          vl.y = (uint32_t)l4[2] | ((uint32_t)l4[3] << 16);
          *(uint2*)&GhR[Gidx(cgi, p, li, cq)] = vh;
          *(uint2*)&GlR[Gidx(cgi, p, li, cq)] = vl;
        } else {
#pragma unroll
          for (int r = 0; r < 4; ++r) {
            int c = cq + r;
            if (c >= 1 && c <= HID) {
              GhR[Gidx(cgi, p, li, c)] = h4[r];
              GlR[Gidx(cgi, p, li, c)] = l4[r];
            }
          }
        }
      }
    }
  }
  __syncthreads();

  // ---- GEMM2: wave = one O-tile, both col-groups; W plain 1x/block ----
  const int mt2 = wid;
  f32x4 acc2[2];
  acc2[0] = (f32x4){0.f, 0.f, 0.f, 0.f};
  acc2[1] = (f32x4){0.f, 0.f, 0.f, 0.f};
  if (mt2 < MT2) {
#pragma unroll
    for (int p = 0; p < 5; ++p) {
#pragma unroll
      for (int kc = 0; kc < NKC; ++kc) {
        bf16x8 bh[2], bl[2];
#pragma unroll
        for (int c2 = 0; c2 < 2; ++c2) {
          bh[c2] = *(const bf16x8*)&GhR[Gidx(c2, p, li, kc * 32 + g * 8)];
          bl[c2] = *(const bf16x8*)&GlR[Gidx(c2, p, li, kc * 32 + g * 8)];
        }
        size_t wa = (((size_t)(p * NKC + kc) * MT2 + mt2) << 9) + lane * 8;
        bf16x8 wh = *(const bf16x8*)(WpkH + wa);
        bf16x8 wl = *(const bf16x8*)(WpkL + wa);
#pragma unroll
        for (int c2 = 0; c2 < 2; ++c2) {
          acc2[c2] = __builtin_amdgcn_mfma_f32_16x16x32_bf16(wh, bh[c2], acc2[c2], 0, 0, 0);
          acc2[c2] = __builtin_amdgcn_mfma_f32_16x16x32_bf16(wh, bl[c2], acc2[c2], 0, 0, 0);
          acc2[c2] = __builtin_amdgcn_mfma_f32_16x16x32_bf16(wl, bh[c2], acc2[c2], 0, 0, 0);
        }
      }
    }
  }

  // ---- rank-1 inputs (c=0 and c=HID), both col-groups ----
  float ch0v[2][5], clv[2][5];
#pragma unroll
  for (int c2 = 0; c2 < 2; ++c2)
#pragma unroll
    for (int p = 0; p < 5; ++p) {
      if (p == 0) {
        size_t a = pk_addr(0, b, nb + c2 * 16 + li);
        ch0v[c2][p] = bf2f(ApkH[a]) + bf2f(ApkL[a]);
      } else {
        ch0v[c2][p] = bf2f(GhR[Gidx(c2, p, li, CH0SLOT)]) +
                      bf2f(GlR[Gidx(c2, p, li, CH0SLOT)]);
      }
      clv[c2][p] = bf2f(GhR[Gidx(c2, p, li, HID)]) + bf2f(GlR[Gidx(c2, p, li, HID)]);
    }

  // ---- epilogue ----
  if (mt2 < MT2) {
#pragma unroll
    for (int c2 = 0; c2 < 2; ++c2) {
      const int ncolx = nb + c2 * 16 + li;
      const int colx = col0 + c2 * 16 + li;
#pragma unroll
      for (int r = 0; r < 4; ++r) {
        int o = mt2 * 16 + 4 * g + r;
        float v = acc2[c2][r] + bias[o];
#pragma unroll
        for (int p = 0; p < 5; ++p) {
          v = fmaf(w0[p * O + o], ch0v[c2][p], v);
          v = fmaf(wlast[p * O + o], clv[c2][p], v);
        }
        size_t a = pk_addr(1 + o, b, ncolx);
        if (MODE == 0) {
          float s = 1.0f / (1.0f + expf(-v));
          if (o < HID) {
            float hrec = bf2f(stH[a]) + bf2f(stL[a]);
            float u = s * hrec;
            u16 h_, l_; split2(u, h_, l_);
            outPkH[a] = h_; outPkL[a] = l_;
          } else {
            rbuf[(size_t)(o - HID) * ROWS + colx] = s;
          }
        } else {
          float hc = tanhf(v);
          float hp = bf2f(stH[a]) + bf2f(stL[a]);
          float rr = rbuf[(size_t)o * ROWS + colx];
          float hn = rr * hp + (1.0f - rr) * hc;
          u16 h_, l_; split2(hn, h_, l_);
          outPkH[a] = h_; outPkL[a] = l_;
          if (MODE == 2) projL[((size_t)c2 * 16 + li) * 100 + o] = hn;
        }
      }
    }
  }

  if (MODE == 0) {
    if (tid < 32) {
      size_t a = pk_addr(0, b, nb + tid);
      outPkH[a] = ApkH[a];
      outPkL[a] = ApkL[a];
    }
  }
  if (MODE == 1) {
    if (tnext >= 0 && tid < 32) {
      int n = nb + tid;
      float xv = xsrc[(size_t)b * (TLEN * NNODE) + (size_t)tnext * NNODE + n];
      u16 h_, l_; split2(xv, h_, l_);
      size_t a = pk_addr(0, b, n);
      outPkH[a] = h_; outPkL[a] = l_;
    }
  }
  if (MODE == 2) {
    __syncthreads();  // projL complete
    if (tid < 32) {
      int n = nb + tid;
      float s = pb[0];
#pragma unroll
      for (int o = 0; o < HID; ++o) s = fmaf(pw[o], projL[(size_t)tid * 100 + o], s);
      u16 h_, l_; split2(s, h_, l_);
      size_t a = pk_addr(0, b, n);
      outPkH[a] = h_; outPkL[a] = l_;
      outp[((size_t)b * TLEN + tcur) * NNODE + n] = s;
    }
  }
}

// 32-block group barrier (group = bid&7; same-XCD L2 shared under round-robin
// dispatch — validated R12). Writers drain (vmcnt(0)); readers use sc0 for
// fresh cross-block data. Arrival atomics are agent-scope (placement-safe).
__device__ __forceinline__ void xcd_barrier(int* bar, int grp, int target) {
  asm volatile("s_waitcnt vmcnt(0)" ::: "memory");
  __syncthreads();
  if (threadIdx.x == 0) {
    __hip_atomic_fetch_add(&bar[grp * 32], 1, __ATOMIC_RELAXED,
                           __HIP_MEMORY_SCOPE_AGENT);
    while (__hip_atomic_load(&bar[grp * 32], __ATOMIC_RELAXED,
                             __HIP_MEMORY_SCOPE_AGENT) < target)
      __builtin_amdgcn_s_sleep(1);
  }
  __syncthreads();
}

// ====================== per-launch fallback kernel ======================
template <int C, int HID, int O, int NKC, int MT1, int MODE>
__global__ __launch_bounds__(1024, 4) void fused_step(
    const u16* __restrict__ ApkH, const u16* __restrict__ ApkL,
    const u16* __restrict__ SpkH, const u16* __restrict__ SpkL,
    const u16* __restrict__ WpkH, const u16* __restrict__ WpkL,
    const float* __restrict__ w0, const float* __restrict__ wlast,
    const float* __restrict__ bias,
    const u16* __restrict__ stH, const u16* __restrict__ stL,
    u16* __restrict__ outPkH, u16* __restrict__ outPkL,
    float* __restrict__ rbuf,
    const float* __restrict__ xsrc, int tnext,
    const float* __restrict__ pw, const float* __restrict__ pb,
    float* __restrict__ outp, int tcur) {
  constexpr int KS8 = (HID + 9) / 8;
  __shared__ __align__(16) u16 GhR[(size_t)2 * 5 * KS8 * 16 * 8];
  __shared__ __align__(16) u16 GlR[(size_t)2 * 5 * KS8 * 16 * 8];
  __shared__ __align__(16) u16 stg[(size_t)MT1 * 8 * 512];
  half_step<C, HID, O, NKC, MT1, MODE>(
      ApkH, ApkL, SpkH, SpkL, WpkH, WpkL, w0, wlast, bias, stH, stL,
      outPkH, outPkL, rbuf, xsrc, tnext, pw, pb, outp, tcur, GhR, GlR, stg);
}

// ====================== persistent phase kernel ======================
struct PhaseP {
  const float* xsrc;
  u16 *hPkH, *hPkL, *uPkH, *uPkL;
  const u16 *SpkH, *SpkL;
  const u16 *WgH, *WgL; const float *w0g, *wlg, *bg;
  const u16 *WuH, *WuL; const float *w0u, *wlu, *bu;
  float* rbuf;
  const float *pw, *pb; float* outp;
  int* bar;
};

template <int C, int HID, int Og, int Ou, int NKC, int MT1, int UPDM>
__global__ __launch_bounds__(1024, 4) void persistent_phase(PhaseP P) {
  constexpr int KS8 = (HID + 9) / 8;
  __shared__ __align__(16) u16 GhR[(size_t)2 * 5 * KS8 * 16 * 8];
  __shared__ __align__(16) u16 GlR[(size_t)2 * 5 * KS8 * 16 * 8];
  __shared__ __align__(16) u16 stg[(size_t)MT1 * 8 * 512];
  const int grp = (int)blockIdx.x & 7;
  int ep = 0;
  for (int t = 0; t < TLEN; ++t) {
    half_step<C, HID, Og, NKC, MT1, 0>(
        P.hPkH, P.hPkL, P.SpkH, P.SpkL, P.WgH, P.WgL, P.w0g, P.wlg, P.bg,
        P.hPkH, P.hPkL, P.uPkH, P.uPkL, P.rbuf, nullptr, -1,
        nullptr, nullptr, nullptr, 0, GhR, GlR, stg);
    ++ep;
    xcd_barrier(P.bar, grp, 32 * ep);
    half_step<C, HID, Ou, NKC, MT1, UPDM>(
        P.uPkH, P.uPkL, P.SpkH, P.SpkL, P.WuH, P.WuL, P.w0u, P.wlu, P.bu,
        P.hPkH, P.hPkL, P.hPkH, P.hPkL, P.rbuf,
        P.xsrc, (UPDM == 1) ? ((t + 1 < TLEN) ? t + 1 : -1) : -1,
        P.pw, P.pb, P.outp, t, GhR, GlR, stg);
    ++ep;
    xcd_barrier(P.bar, grp, 32 * ep);
  }
}

// ====================== host launch ======================
extern "C" void kernel_launch(void* const* d_in, const int* in_sizes, int n_in,
                              void* d_out, int out_size, void* d_ws, size_t ws_size,
                              hipStream_t stream) {
  (void)in_sizes; (void)n_in; (void)out_size; (void)ws_size;
  const float* x   = (const float*)d_in[0];
  const float* Mem = (const float*)d_in[1];
  const float* Wq  = (const float*)d_in[2];
  const float* We1 = (const float*)d_in[3];
  const float* We2 = (const float*)d_in[4];
  const float* egw = (const float*)d_in[5];
  const float* egb = (const float*)d_in[6];
  const float* euw = (const float*)d_in[7];
  const float* eub = (const float*)d_in[8];
  const float* dgw = (const float*)d_in[9];
  const float* dgb = (const float*)d_in[10];
  const float* duw = (const float*)d_in[11];
  const float* dub = (const float*)d_in[12];
  const float* pw  = (const float*)d_in[13];
  const float* pb  = (const float*)d_in[14];
  float* out = (float*)d_out;

  float* ws = (float*)d_ws;
  size_t off = 0;
  auto allocf = [&](size_t nf) {
    float* p = ws + off;
    off += (nf + 63) & ~(size_t)63;
    return p;
  };
  auto allocu = [&](size_t nu) { return (u16*)allocf((nu + 1) / 2); };

  float* Sf  = allocf(4 * 65536);
  float* e1  = allocf(8192);
  float* e2  = allocf(8192);
  float* n1  = allocf(256);
  float* n2  = allocf(256);
  float* adj = allocf(65536);
  float* deg = allocf(256);
  int* stats = (int*)allocf(64);
  float* rb  = allocf((size_t)96 * ROWS);
  float* w0gE = allocf(5 * 128);
  float* w0uE = allocf(5 * 64);
  float* w0gD = allocf(5 * 192);
  float* w0uD = allocf(5 * 96);
  float* wlgE = allocf(5 * 128);
  float* wluE = allocf(5 * 64);
  float* wlgD = allocf(5 * 192);
  float* wluD = allocf(5 * 96);

  u16* SpkH = allocu((size_t)4 * 65536);
  u16* SpkL = allocu((size_t)4 * 65536);
  u16* WgEh = allocu((size_t)5 * 2 * 8 * 512);
  u16* WgEl = allocu((size_t)5 * 2 * 8 * 512);
  u16* WuEh = allocu((size_t)5 * 2 * 4 * 512);
  u16* WuEl = allocu((size_t)5 * 2 * 4 * 512);
  u16* WgDh = allocu((size_t)5 * 3 * 12 * 512);
  u16* WgDl = allocu((size_t)5 * 3 * 12 * 512);
  u16* WuDh = allocu((size_t)5 * 3 * 6 * 512);
  u16* WuDl = allocu((size_t)5 * 3 * 6 * 512);

  // packed states — contiguous for one-shot zero init; then barriers
  const size_t PKE = (size_t)5 * 32 * 8 * 512;
  const size_t PKD = (size_t)7 * 32 * 8 * 512;
  u16* hEpkH = allocu(PKE);
  u16* hEpkL = allocu(PKE);
  u16* uEpkH = allocu(PKE);
  u16* uEpkL = allocu(PKE);
  u16* hDpkH = allocu(PKD);
  u16* hDpkL = allocu(PKD);
  u16* uDpkH = allocu(PKD);
  u16* uDpkL = allocu(PKD);
  const size_t PKTOT = 4 * PKE + 4 * PKD;
  int* barE = (int*)allocf(256);
  int* barD = (int*)allocf(256);

  // ---- PRNG keys (jax partitionable threefry) ----
  uint32_t ka0, ka1, kb0, kb1;
  tf2x32(0u, 42u, 0u, 0u, &ka0, &ka1);
  tf2x32(0u, 42u, 0u, 1u, &kb0, &kb1);

  // ---- init + graph setup ----
  zero_kernel<<<1024, 256, 0, stream>>>((uint4*)hEpkH, (int)(PKTOT / 8));
  zero_kernel<<<1, 256, 0, stream>>>((uint4*)barE, 128);  // barE+barD contiguous
  setup_embed_kernel<<<1, 256, 0, stream>>>(We1, We2, Mem, e1, e2, n1, n2);
  stats_init_kernel<<<1, 1, 0, stream>>>(stats);
  adj_kernel<<<256, 256, 0, stream>>>(e1, e2, n1, n2, ka0, ka1, adj, deg, stats);
  lap_kernel<<<256, 256, 0, stream>>>(adj, deg, stats, Sf);
  t2_kernel<<<dim3(4, 4), 256, 0, stream>>>(Sf, Sf + 65536);
  stats_init_kernel<<<1, 1, 0, stream>>>(stats);
  adj_kernel<<<256, 256, 0, stream>>>(e2, e1, n2, n1, kb0, kb1, adj, deg, stats);
  lap_kernel<<<256, 256, 0, stream>>>(adj, deg, stats, Sf + 2 * 65536);
  t2_kernel<<<dim3(4, 4), 256, 0, stream>>>(Sf + 2 * 65536, Sf + 3 * 65536);
  cvt_s_packed<<<1024, 256, 0, stream>>>(Sf, SpkH, SpkL);
  build_wfrag<<<(5 * 64 * 128 + 255) / 256, 256, 0, stream>>>(egw, 65, 128, 64, WgEh, WgEl, w0gE, wlgE);
  build_wfrag<<<(5 * 64 * 64 + 255) / 256, 256, 0, stream>>>(euw, 65, 64, 64, WuEh, WuEl, w0uE, wluE);
  build_wfrag<<<(5 * 96 * 192 + 255) / 256, 256, 0, stream>>>(dgw, 97, 192, 96, WgDh, WgDl, w0gD, wlgD);
  build_wfrag<<<(5 * 96 * 96 + 255) / 256, 256, 0, stream>>>(duw, 97, 96, 96, WuDh, WuDl, w0uD, wluD);

  // ---- encoder ----
  enc_init<<<32, 256, 0, stream>>>(x, hEpkH, hEpkL);
  {
    PhaseP pe;
    pe.xsrc = x;
    pe.hPkH = hEpkH; pe.hPkL = hEpkL; pe.uPkH = uEpkH; pe.uPkL = uEpkL;
    pe.SpkH = SpkH; pe.SpkL = SpkL;
    pe.WgH = WgEh; pe.WgL = WgEl; pe.w0g = w0gE; pe.wlg = wlgE; pe.bg = egb;
    pe.WuH = WuEh; pe.WuL = WuEl; pe.w0u = w0uE; pe.wlu = wluE; pe.bu = eub;
    pe.rbuf = rb; pe.pw = nullptr; pe.pb = nullptr; pe.outp = nullptr;
    pe.bar = barE;
    void* argsE[] = { &pe };
    auto kE = persistent_phase<65, 64, 128, 64, 2, 5, 1>;
    hipError_t e = hipLaunchCooperativeKernel((const void*)kE, dim3(256),
                                              dim3(1024), argsE, 0, stream);
    if (e != hipSuccess) {
      for (int t = 0; t < TLEN; ++t) {
        fused_step<65, 64, 128, 2, 5, 0><<<256, 1024, 0, stream>>>(
            hEpkH, hEpkL, SpkH, SpkL, WgEh, WgEl, w0gE, wlgE, egb,
            hEpkH, hEpkL, uEpkH, uEpkL, rb, nullptr, -1, nullptr, nullptr, nullptr, 0);
        fused_step<65, 64, 64, 2, 5, 1><<<256, 1024, 0, stream>>>(
            uEpkH, uEpkL, SpkH, SpkL, WuEh, WuEl, w0uE, wluE, eub,
            hEpkH, hEpkL, hEpkH, hEpkL, rb,
            x, (t + 1 < TLEN) ? (t + 1) : -1, nullptr, nullptr, nullptr, 0);
      }
    }
  }

  // ---- attention + decoder init ----
  attn2<<<64, 128, 0, stream>>>(hEpkH, hEpkL, Wq, Mem, hDpkH, hDpkL);

  // ---- decoder ----
  {
    PhaseP pd;
    pd.xsrc = nullptr;
    pd.hPkH = hDpkH; pd.hPkL = hDpkL; pd.uPkH = uDpkH; pd.uPkL = uDpkL;
    pd.SpkH = SpkH; pd.SpkL = SpkL;
    pd.WgH = WgDh; pd.WgL = WgDl; pd.w0g = w0gD; pd.wlg = wlgD; pd.bg = dgb;
    pd.WuH = WuDh; pd.WuL = WuDl; pd.w0u = w0uD; pd.wlu = wluD; pd.bu = dub;
    pd.rbuf = rb; pd.pw = pw; pd.pb = pb; pd.outp = out;
    pd.bar = barD;
    void* argsD[] = { &pd };
    auto kD = persistent_phase<97, 96, 192, 96, 3, 7, 2>;
    hipError_t e = hipLaunchCooperativeKernel((const void*)kD, dim3(256),
                                              dim3(1024), argsD, 0, stream);
    if (e != hipSuccess) {
      for (int t = 0; t < TLEN; ++t) {
        fused_step<97, 96, 192, 3, 7, 0><<<256, 1024, 0, stream>>>(
            hDpkH, hDpkL, SpkH, SpkL, WgDh, WgDl, w0gD, wlgD, dgb,
            hDpkH, hDpkL, uDpkH, uDpkL, rb, nullptr, -1, nullptr, nullptr, nullptr, 0);
        fused_step<97, 96, 96, 3, 7, 2><<<256, 1024, 0, stream>>>(
            uDpkH, uDpkL, SpkH, SpkL, WuDh, WuDl, w0uD, wluD, dub,
            hDpkH, hDpkL, hDpkH, hDpkL, rb,
            nullptr, -1, pw, pb, out, t);
      }
    }
  }
}

// Round 15
// 9206.417 us; speedup vs baseline: 2.3567x; 2.3567x over previous
//
#include <hip/hip_runtime.h>
#include <stdint.h>
#include <math.h>

// ====================== problem constants ======================
#define NNODE 256
#define BATCH 32
#define TLEN  128
#define ROWS  8192 // NNODE*BATCH

typedef unsigned short u16;
typedef short bf16x8 __attribute__((ext_vector_type(8)));
typedef float f32x4 __attribute__((ext_vector_type(4)));

__device__ inline u16 f2bf_rn(float v) {
  uint32_t u = __float_as_uint(v);
  u += 0x7fffu + ((u >> 16) & 1u);
  return (u16)(u >> 16);
}
__device__ inline float bf2f(u16 h) { return __uint_as_float(((uint32_t)h) << 16); }
__device__ inline void split2(float v, u16& hi, u16& lo) {
  hi = f2bf_rn(v);
  lo = f2bf_rn(v - bf2f(hi));
}

// packed-state element address: fragment (ct=c/16, b, mc=n/32), lane-major
__device__ inline size_t pk_addr(int c, int b, int n) {
  return ((((size_t)(c >> 4) * 32 + b) * 8 + (n >> 5)) << 9) +
         (((size_t)((c & 15) | (((n >> 3) & 3) << 4))) << 3) + (n & 7);
}

// ====================== Threefry-2x32 (20 rounds) ======================
__host__ __device__ inline uint32_t rotl32_(uint32_t v, int d) {
  return (v << d) | (v >> (32 - d));
}
__host__ __device__ inline void tf2x32(uint32_t k0, uint32_t k1, uint32_t x0,
                                       uint32_t x1, uint32_t* o0, uint32_t* o1) {
  uint32_t ks2 = k0 ^ k1 ^ 0x1BD11BDAu;
  x0 += k0; x1 += k1;
  x0 += x1; x1 = rotl32_(x1, 13); x1 ^= x0;
  x0 += x1; x1 = rotl32_(x1, 15); x1 ^= x0;
  x0 += x1; x1 = rotl32_(x1, 26); x1 ^= x0;
  x0 += x1; x1 = rotl32_(x1, 6);  x1 ^= x0;
  x0 += k1; x1 += ks2 + 1u;
  x0 += x1; x1 = rotl32_(x1, 17); x1 ^= x0;
  x0 += x1; x1 = rotl32_(x1, 29); x1 ^= x0;
  x0 += x1; x1 = rotl32_(x1, 16); x1 ^= x0;
  x0 += x1; x1 = rotl32_(x1, 24); x1 ^= x0;
  x0 += ks2; x1 += k0 + 2u;
  x0 += x1; x1 = rotl32_(x1, 13); x1 ^= x0;
  x0 += x1; x1 = rotl32_(x1, 15); x1 ^= x0;
  x0 += x1; x1 = rotl32_(x1, 26); x1 ^= x0;
  x0 += x1; x1 = rotl32_(x1, 6);  x1 ^= x0;
  x0 += k0; x1 += k1 + 3u;
  x0 += x1; x1 = rotl32_(x1, 17); x1 ^= x0;
  x0 += x1; x1 = rotl32_(x1, 29); x1 ^= x0;
  x0 += x1; x1 = rotl32_(x1, 16); x1 ^= x0;
  x0 += x1; x1 = rotl32_(x1, 24); x1 ^= x0;
  x0 += k1; x1 += ks2 + 4u;
  x0 += x1; x1 = rotl32_(x1, 13); x1 ^= x0;
  x0 += x1; x1 = rotl32_(x1, 15); x1 ^= x0;
  x0 += x1; x1 = rotl32_(x1, 26); x1 ^= x0;
  x0 += x1; x1 = rotl32_(x1, 6);  x1 ^= x0;
  x0 += ks2; x1 += k0 + 5u;
  *o0 = x0; *o1 = x1;
}

__device__ inline float gumbel_at(uint32_t k0, uint32_t k1, uint32_t idx) {
  uint32_t o0, o1;
  tf2x32(k0, k1, 0u, idx, &o0, &o1);
  uint32_t b = o0 ^ o1;
  float f = __uint_as_float((b >> 9) | 0x3f800000u) - 1.0f;
  const float tiny = 1.17549435e-38f;
  float u = fmaxf(tiny, f + tiny);
  return -logf(-logf(u));
}

// ====================== graph setup kernels (fp32, one-time) ======================
__global__ __launch_bounds__(256) void setup_embed_kernel(
    const float* __restrict__ We1, const float* __restrict__ We2,
    const float* __restrict__ Mem, float* __restrict__ e1, float* __restrict__ e2,
    float* __restrict__ n1, float* __restrict__ n2) {
  int n = threadIdx.x;
  float a[8];
  float s;
  for (int m = 0; m < 8; ++m) a[m] = We1[n * 8 + m];
  s = 0.f;
  for (int j = 0; j < 32; ++j) {
    float v = 0.f;
    for (int m = 0; m < 8; ++m) v = fmaf(a[m], Mem[m * 32 + j], v);
    e1[n * 32 + j] = v;
    s = fmaf(v, v, s);
  }
  n1[n] = sqrtf(s);
  for (int m = 0; m < 8; ++m) a[m] = We2[n * 8 + m];
  s = 0.f;
  for (int j = 0; j < 32; ++j) {
    float v = 0.f;
    for (int m = 0; m < 8; ++m) v = fmaf(a[m], Mem[m * 32 + j], v);
    e2[n * 32 + j] = v;
    s = fmaf(v, v, s);
  }
  n2[n] = sqrtf(s);
}

__global__ void stats_init_kernel(int* stats) {
  stats[0] = 0;
  stats[1] = 0;
  stats[2] = 0x7fffffff;
}

__global__ __launch_bounds__(256) void adj_kernel(
    const float* __restrict__ eA, const float* __restrict__ eB,
    const float* __restrict__ nA, const float* __restrict__ nB,
    uint32_t k0, uint32_t k1, float* __restrict__ adj, float* __restrict__ deg,
    int* __restrict__ stats) {
  int i = blockIdx.x, j = threadIdx.x;
  float dot = 0.f;
  for (int c = 0; c < 32; ++c) dot = fmaf(eA[i * 32 + c], eB[j * 32 + c], dot);
  float g = dot / (nA[i] * nB[j] + 1e-6f);
  g = (g + 1.0f) * 0.5f;
  uint32_t f = ((uint32_t)(i * 256 + j)) * 2u;
  float g0 = gumbel_at(k0, k1, f);
  float g1 = gumbel_at(k0, k1, f + 1u);
  float a = ((g + g0) >= ((1.0f - g) + g1)) ? 1.0f : 0.0f;
  if (i == j) a = 0.0f;
  adj[i * 256 + j] = a;
  __shared__ float red[256];
  red[j] = a;
  __syncthreads();
  for (int s = 128; s > 0; s >>= 1) {
    if (j < s) red[j] += red[j + s];
    __syncthreads();
  }
  if (j == 0) {
    float d = red[0];
    deg[i] = d;
    atomicMax(&stats[0], (int)d);
    atomicMin(&stats[2], (int)d);
    if (d > 0.5f) atomicOr(&stats[1], 1);
  }
}

__global__ __launch_bounds__(256) void lap_kernel(const float* __restrict__ adj,
                                                  const float* __restrict__ deg,
                                                  const int* __restrict__ stats,
                                                  float* __restrict__ S1) {
  int i = blockIdx.x, j = threadIdx.x;
  float lmax = (float)stats[0];
  float lmin = stats[1] ? -1.0f : (float)stats[2];
  float lam = lmax - lmin;
  float L = (i == j) ? deg[i] : -adj[i * 256 + j];
  S1[i * 256 + j] = 2.0f * L / lam - ((i == j) ? 1.0f : 0.0f);
}

// T2 = 2*(S1@S1) - I  (fp32 VALU tile GEMM, one-time)
__global__ __launch_bounds__(256) void t2_kernel(const float* __restrict__ A,
                                                 float* __restrict__ Cout) {
  __shared__ __align__(16) float sAT[32][68];
  __shared__ __align__(16) float sB[32][68];
  int tid = threadIdx.x;
  int tc = tid & 15, tr = tid >> 4;
  int row0 = blockIdx.y * 64, col0 = blockIdx.x * 64;
  float acc[4][4] = {};
  for (int m0 = 0; m0 < 256; m0 += 32) {
    for (int i = tid; i < 2048; i += 256) {
      int r = i >> 5, c = i & 31;
      sAT[c][r] = A[(size_t)(row0 + r) * 256 + m0 + c];
    }
    for (int i = tid; i < 2048; i += 256) {
      int r = i >> 6, c = i & 63;
      sB[r][c] = A[(size_t)(m0 + r) * 256 + col0 + c];
    }
    __syncthreads();
#pragma unroll
    for (int kk = 0; kk < 32; ++kk) {
      float4 av = *(const float4*)&sAT[kk][tr * 4];
      float4 bv = *(const float4*)&sB[kk][tc * 4];
      float a[4] = {av.x, av.y, av.z, av.w};
      float b[4] = {bv.x, bv.y, bv.z, bv.w};
#pragma unroll
      for (int i = 0; i < 4; ++i)
#pragma unroll
        for (int j = 0; j < 4; ++j) acc[i][j] = fmaf(a[i], b[j], acc[i][j]);
    }
    __syncthreads();
  }
#pragma unroll
  for (int i = 0; i < 4; ++i) {
    int row = row0 + tr * 4 + i;
#pragma unroll
    for (int j = 0; j < 4; ++j) {
      int col = col0 + tc * 4 + j;
      Cout[(size_t)row * 256 + col] = 2.0f * acc[i][j] - ((row == col) ? 1.0f : 0.0f);
    }
  }
}

// S fp32 -> fragment-packed hi/lo bf16
__global__ void cvt_s_packed(const float* __restrict__ S, u16* __restrict__ Sh,
                             u16* __restrict__ Sl) {
  int idx = blockIdx.x * 256 + threadIdx.x;
  if (idx >= 4 * 65536) return;
  int p = idx >> 16, rem = idx & 65535;
  int n = rem >> 8, m = rem & 255;
  int nt = n >> 4, li = n & 15;
  int mc = m >> 5, g = (m >> 3) & 3, j = m & 7;
  int lane = li | (g << 4);
  size_t a = (((size_t)(p * 16 + nt) * 8 + mc) << 9) + lane * 8 + j;
  u16 h, l;
  split2(S[idx], h, l);
  Sh[a] = h; Sl[a] = l;
}

// W fragment-packed (k=3 folded into p=0; c==0/c==hid via rank-1 w0/wlast)
__global__ void build_wfrag(const float* __restrict__ W, int C, int O, int hid,
                            u16* __restrict__ WfH, u16* __restrict__ WfL,
                            float* __restrict__ w0, float* __restrict__ wlast) {
  int idx = blockIdx.x * 256 + threadIdx.x;
  int nKC = hid / 32;
  if (idx < 5 * hid * O) {
    int kk = idx & 31;
    int rest = idx >> 5;
    int o = rest % O; rest /= O;
    int kc = rest % nKC;
    int p = rest / nKC;
    int korig = (p == 0) ? 0 : (p + (p >= 3 ? 1 : 0));
    int c = kc * 32 + kk;
    float v = 0.f;
    if (c > 0) {
      v = W[(size_t)(korig * C + c) * O + o];
      if (p == 0) v += W[(size_t)(3 * C + c) * O + o];
    }
    int ot = o >> 4, li = o & 15, g = kk >> 3, j = kk & 7;
    int lane = li | (g << 4);
    size_t a = (((size_t)(p * nKC + kc) * (O / 16) + ot) << 9) + lane * 8 + j;
    u16 h, l; split2(v, h, l);
    WfH[a] = h; WfL[a] = l;
  }
  if (idx < 5 * O) {
    int o = idx % O, p = idx / O;
    int korig = (p == 0) ? 0 : (p + (p >= 3 ? 1 : 0));
    float v0 = W[(size_t)(korig * C + 0) * O + o];
    if (p == 0) v0 += W[(size_t)(3 * C + 0) * O + o];
    w0[p * O + o] = v0;
    float vl = W[(size_t)(korig * C + hid) * O + o];
    if (p == 0) vl += W[(size_t)(3 * C + hid) * O + o];
    wlast[p * O + o] = vl;
  }
}

__global__ void zero_kernel(uint4* __restrict__ p, int n4) {
  for (int i = blockIdx.x * blockDim.x + threadIdx.x; i < n4;
       i += gridDim.x * blockDim.x)
    p[i] = make_uint4(0, 0, 0, 0);
}

// encoder state init: packed ch0 = x[:,0] (rest already zeroed)
__global__ void enc_init(const float* __restrict__ x,
                         u16* __restrict__ pkh, u16* __restrict__ pkl) {
  int col = blockIdx.x * 256 + threadIdx.x;
  if (col >= ROWS) return;
  int b = col >> 8, n = col & 255;
  float v = x[(size_t)b * (TLEN * NNODE) + n];
  u16 h, l; split2(v, h, l);
  size_t a = pk_addr(0, b, n);
  pkh[a] = h; pkl[a] = l;
}

// attention + decoder state init (packed only)
__global__ __launch_bounds__(128) void attn2(const u16* __restrict__ hEh,
                                             const u16* __restrict__ hEl,
                                             const float* __restrict__ Wq,
                                             const float* __restrict__ Mem,
                                             u16* __restrict__ pkh,
                                             u16* __restrict__ pkl) {
  int col = blockIdx.x * 128 + threadIdx.x;
  int b = col >> 8, n = col & 255;
  float h[64];
  for (int c = 0; c < 64; ++c) {
    size_t a = pk_addr(1 + c, b, n);
    h[c] = bf2f(hEh[a]) + bf2f(hEl[a]);
  }
  float q[32];
  for (int j = 0; j < 32; ++j) {
    float s = 0.f;
    for (int c = 0; c < 64; ++c) s = fmaf(h[c], Wq[c * 32 + j], s);
    q[j] = s;
  }
  float l[8], mx = -3.402823466e38f;
  for (int m = 0; m < 8; ++m) {
    float s = 0.f;
    for (int j = 0; j < 32; ++j) s = fmaf(q[j], Mem[m * 32 + j], s);
    l[m] = s;
    mx = fmaxf(mx, s);
  }
  float se = 0.f;
  for (int m = 0; m < 8; ++m) { l[m] = expf(l[m] - mx); se += l[m]; }
  float val[32];
  for (int j = 0; j < 32; ++j) {
    float v = 0.f;
    for (int m = 0; m < 8; ++m) v = fmaf(l[m] / se, Mem[m * 32 + j], v);
    val[j] = v;
  }
  for (int c = 0; c < 97; ++c) {
    float v = (c == 0) ? 0.f : ((c <= 64) ? h[c - 1] : val[c - 65]);
    u16 hh, ll; split2(v, hh, ll);
    size_t a = pk_addr(c, b, n);
    pkh[a] = hh; pkl[a] = ll;
  }
}

// ====================== fused half-step kernel ======================
// R13 structure with 16-col blocks (grid 512 = 2 blocks/CU): halves the
// per-block serial chain and lets two independent blocks interleave per CU.
// Per-output MFMA/operand order unchanged -> numerics identical to R13.
// GEMM1: wave = (pp=wid&3 S-piece, seg=wid>>2 quarter of c-tiles), MT1A=2.
// GEMM2: wave = one O-tile (mt2 = wid). W loaded once per block.
template <int C, int HID, int O, int NKC, int MT1, int MODE>
__global__ __launch_bounds__(1024, 8) void fused_step(
    const u16* __restrict__ ApkH, const u16* __restrict__ ApkL,
    const u16* __restrict__ SpkH, const u16* __restrict__ SpkL,
    const u16* __restrict__ WpkH, const u16* __restrict__ WpkL,
    const float* __restrict__ w0, const float* __restrict__ wlast,
    const float* __restrict__ bias,
    const u16* __restrict__ stH, const u16* __restrict__ stL,
    u16* __restrict__ outPkH, u16* __restrict__ outPkL,
    float* __restrict__ rbuf,
    const float* __restrict__ xsrc, int tnext,
    const float* __restrict__ pw, const float* __restrict__ pb,
    float* __restrict__ outp, int tcur) {
  constexpr int MT2 = O / 16;
  constexpr int MT1A = (MT1 + 3) / 4;
  constexpr int CH0SLOT = HID + 1;
  constexpr int KS8 = (HID + 9) / 8;

  __shared__ __align__(16) u16 GhR[(size_t)5 * KS8 * 16 * 8];
  __shared__ __align__(16) u16 GlR[(size_t)5 * KS8 * 16 * 8];
  __shared__ float projL[(MODE == 2) ? 16 * 100 : 4];

  auto Gidx = [](int p, int li, int slot) -> size_t {
    return (((size_t)(p * KS8 + (slot >> 3)) * 16 + li) << 3) + (slot & 7);
  };

  const int tid = threadIdx.x;
  const int wid = tid >> 6, lane = tid & 63;
  const int g = lane >> 4, li = lane & 15;
  const int pp = wid & 3, seg = wid >> 2;
  // XCD swizzle for 512 blocks: 8 groups of 64 contiguous-col blocks
  const int bid0 = (int)blockIdx.x;
  const int bidx = ((bid0 & 7) << 6) | (bid0 >> 3);
  const int col0 = bidx * 16;
  const int b = col0 >> 8;
  const int nb = col0 & 255;
  const int nt = nb >> 4;

  // ---- stage G_0: raw copy of packed state (bit-identical) ----
  for (int i = tid; i < 16 * C; i += 1024) {
    int c = i >> 4, q = i & 15;
    size_t a = pk_addr(c, b, nb + q);
    int slot = (c == 0) ? CH0SLOT : c;
    GhR[Gidx(0, q, slot)] = ApkH[a];
    GlR[Gidx(0, q, slot)] = ApkL[a];
  }
  if (tid < 16) {
    GhR[Gidx(0, tid, 0)] = 0;
    GlR[Gidx(0, tid, 0)] = 0;
  }

  // ---- GEMM1: wave owns (S-piece pp, quarter seg of c-tiles) ----
  f32x4 acc1[MT1A];
#pragma unroll
  for (int i = 0; i < MT1A; ++i) acc1[i] = (f32x4){0.f, 0.f, 0.f, 0.f};

#pragma unroll 2
  for (int mc = 0; mc < 8; ++mc) {
    size_t sa = (((size_t)(pp * 16 + nt) * 8 + mc) << 9) + lane * 8;
    bf16x8 sbh = *(const bf16x8*)(SpkH + sa);
    bf16x8 sbl = *(const bf16x8*)(SpkL + sa);
#pragma unroll
    for (int i = 0; i < MT1A; ++i) {
      const int mt = seg * MT1A + i;
      if (mt < MT1) {
        size_t aa = (((size_t)(mt * 32 + b) * 8 + mc) << 9) + lane * 8;
        bf16x8 ah = *(const bf16x8*)(ApkH + aa);
        bf16x8 al = *(const bf16x8*)(ApkL + aa);
        acc1[i] = __builtin_amdgcn_mfma_f32_16x16x32_bf16(ah, sbh, acc1[i], 0, 0, 0);
        acc1[i] = __builtin_amdgcn_mfma_f32_16x16x32_bf16(ah, sbl, acc1[i], 0, 0, 0);
        acc1[i] = __builtin_amdgcn_mfma_f32_16x16x32_bf16(al, sbh, acc1[i], 0, 0, 0);
      }
    }
  }

  // ---- epi1: split + write G_{pp+1} to LDS ----
  {
    const int p = pp + 1;
#pragma unroll
    for (int i = 0; i < MT1A; ++i) {
      const int mt = seg * MT1A + i;
      if (mt < MT1) {
        int cq = mt * 16 + 4 * g;
        u16 h4[4], l4[4];
#pragma unroll
        for (int r = 0; r < 4; ++r) split2(acc1[i][r], h4[r], l4[r]);
        if (cq == 0) {
          GhR[Gidx(p, li, CH0SLOT)] = h4[0];
          GlR[Gidx(p, li, CH0SLOT)] = l4[0];
          h4[0] = 0; l4[0] = 0;
        }
        if (cq + 3 <= HID) {
          uint2 vh, vl;
          vh.x = (uint32_t)h4[0] | ((uint32_t)h4[1] << 16);
          vh.y = (uint32_t)h4[2] | ((uint32_t)h4[3] << 16);
          vl.x = (uint32_t)l4[0] | ((uint32_t)l4[1] << 16);
          vl.y = (uint32_t)l4[2] | ((uint32_t)l4[3] << 16);
          *(uint2*)&GhR[Gidx(p, li, cq)] = vh;
          *(uint2*)&GlR[Gidx(p, li, cq)] = vl;
        } else {
#pragma unroll
          for (int r = 0; r < 4; ++r) {
            int c = cq + r;
            if (c >= 1 && c <= HID) {
              GhR[Gidx(p, li, c)] = h4[r];
              GlR[Gidx(p, li, c)] = l4[r];
            }
          }
        }
      }
    }
  }
  __syncthreads();

  // ---- GEMM2: wave = one O-tile; W 1x/block ----
  const int mt2 = wid;
  f32x4 acc2 = (f32x4){0.f, 0.f, 0.f, 0.f};
  if (mt2 < MT2) {
#pragma unroll
    for (int p = 0; p < 5; ++p) {
#pragma unroll
      for (int kc = 0; kc < NKC; ++kc) {
        bf16x8 bh = *(const bf16x8*)&GhR[Gidx(p, li, kc * 32 + g * 8)];
        bf16x8 bl = *(const bf16x8*)&GlR[Gidx(p, li, kc * 32 + g * 8)];
        size_t wa = (((size_t)(p * NKC + kc) * MT2 + mt2) << 9) + lane * 8;
        bf16x8 wh = *(const bf16x8*)(WpkH + wa);
        bf16x8 wl = *(const bf16x8*)(WpkL + wa);
        acc2 = __builtin_amdgcn_mfma_f32_16x16x32_bf16(wh, bh, acc2, 0, 0, 0);
        acc2 = __builtin_amdgcn_mfma_f32_16x16x32_bf16(wh, bl, acc2, 0, 0, 0);
        acc2 = __builtin_amdgcn_mfma_f32_16x16x32_bf16(wl, bh, acc2, 0, 0, 0);
      }
    }
  }

  // ---- rank-1 inputs (c=0 and c=HID) ----
  float ch0v[5], clv[5];
#pragma unroll
  for (int p = 0; p < 5; ++p) {
    if (p == 0) {
      size_t a = pk_addr(0, b, nb + li);
      ch0v[p] = bf2f(ApkH[a]) + bf2f(ApkL[a]);
    } else {
      ch0v[p] = bf2f(GhR[Gidx(p, li, CH0SLOT)]) + bf2f(GlR[Gidx(p, li, CH0SLOT)]);
    }
    clv[p] = bf2f(GhR[Gidx(p, li, HID)]) + bf2f(GlR[Gidx(p, li, HID)]);
  }

  // ---- epilogue ----
  if (mt2 < MT2) {
    const int ncolx = nb + li;
    const int colx = col0 + li;
#pragma unroll
    for (int r = 0; r < 4; ++r) {
      int o = mt2 * 16 + 4 * g + r;
      float v = acc2[r] + bias[o];
#pragma unroll
      for (int p = 0; p < 5; ++p) {
        v = fmaf(w0[p * O + o], ch0v[p], v);
        v = fmaf(wlast[p * O + o], clv[p], v);
      }
      size_t a = pk_addr(1 + o, b, ncolx);
      if (MODE == 0) {
        float s = 1.0f / (1.0f + expf(-v));
        if (o < HID) {
          float hrec = bf2f(stH[a]) + bf2f(stL[a]);
          float u = s * hrec;
          u16 h_, l_; split2(u, h_, l_);
          outPkH[a] = h_; outPkL[a] = l_;
        } else {
          rbuf[(size_t)(o - HID) * ROWS + colx] = s;
        }
      } else {
        float hc = tanhf(v);
        float hp = bf2f(stH[a]) + bf2f(stL[a]);
        float rr = rbuf[(size_t)o * ROWS + colx];
        float hn = rr * hp + (1.0f - rr) * hc;
        u16 h_, l_; split2(hn, h_, l_);
        outPkH[a] = h_; outPkL[a] = l_;
        if (MODE == 2) projL[(size_t)li * 100 + o] = hn;
      }
    }
  }

  if (MODE == 0) {
    if (tid < 16) {
      size_t a = pk_addr(0, b, nb + tid);
      outPkH[a] = ApkH[a];
      outPkL[a] = ApkL[a];
    }
  }
  if (MODE == 1) {
    if (tnext >= 0 && tid < 16) {
      int n = nb + tid;
      float xv = xsrc[(size_t)b * (TLEN * NNODE) + (size_t)tnext * NNODE + n];
      u16 h_, l_; split2(xv, h_, l_);
      size_t a = pk_addr(0, b, n);
      outPkH[a] = h_; outPkL[a] = l_;
    }
  }
  if (MODE == 2) {
    __syncthreads();  // projL complete
    if (tid < 16) {
      int n = nb + tid;
      float s = pb[0];
#pragma unroll
      for (int o = 0; o < HID; ++o) s = fmaf(pw[o], projL[(size_t)tid * 100 + o], s);
      u16 h_, l_; split2(s, h_, l_);
      size_t a = pk_addr(0, b, n);
      outPkH[a] = h_; outPkL[a] = l_;
      outp[((size_t)b * TLEN + tcur) * NNODE + n] = s;
    }
  }
}

// ====================== host launch ======================
extern "C" void kernel_launch(void* const* d_in, const int* in_sizes, int n_in,
                              void* d_out, int out_size, void* d_ws, size_t ws_size,
                              hipStream_t stream) {
  (void)in_sizes; (void)n_in; (void)out_size; (void)ws_size;
  const float* x   = (const float*)d_in[0];
  const float* Mem = (const float*)d_in[1];
  const float* Wq  = (const float*)d_in[2];
  const float* We1 = (const float*)d_in[3];
  const float* We2 = (const float*)d_in[4];
  const float* egw = (const float*)d_in[5];
  const float* egb = (const float*)d_in[6];
  const float* euw = (const float*)d_in[7];
  const float* eub = (const float*)d_in[8];
  const float* dgw = (const float*)d_in[9];
  const float* dgb = (const float*)d_in[10];
  const float* duw = (const float*)d_in[11];
  const float* dub = (const float*)d_in[12];
  const float* pw  = (const float*)d_in[13];
  const float* pb  = (const float*)d_in[14];
  float* out = (float*)d_out;

  float* ws = (float*)d_ws;
  size_t off = 0;
  auto allocf = [&](size_t nf) {
    float* p = ws + off;
    off += (nf + 63) & ~(size_t)63;
    return p;
  };
  auto allocu = [&](size_t nu) { return (u16*)allocf((nu + 1) / 2); };

  float* Sf  = allocf(4 * 65536);
  float* e1  = allocf(8192);
  float* e2  = allocf(8192);
  float* n1  = allocf(256);
  float* n2  = allocf(256);
  float* adj = allocf(65536);
  float* deg = allocf(256);
  int* stats = (int*)allocf(64);
  float* rb  = allocf((size_t)96 * ROWS);
  float* w0gE = allocf(5 * 128);
  float* w0uE = allocf(5 * 64);
  float* w0gD = allocf(5 * 192);
  float* w0uD = allocf(5 * 96);
  float* wlgE = allocf(5 * 128);
  float* wluE = allocf(5 * 64);
  float* wlgD = allocf(5 * 192);
  float* wluD = allocf(5 * 96);

  u16* SpkH = allocu((size_t)4 * 65536);
  u16* SpkL = allocu((size_t)4 * 65536);
  u16* WgEh = allocu((size_t)5 * 2 * 8 * 512);
  u16* WgEl = allocu((size_t)5 * 2 * 8 * 512);
  u16* WuEh = allocu((size_t)5 * 2 * 4 * 512);
  u16* WuEl = allocu((size_t)5 * 2 * 4 * 512);
  u16* WgDh = allocu((size_t)5 * 3 * 12 * 512);
  u16* WgDl = allocu((size_t)5 * 3 * 12 * 512);
  u16* WuDh = allocu((size_t)5 * 3 * 6 * 512);
  u16* WuDl = allocu((size_t)5 * 3 * 6 * 512);

  // packed states — contiguous for one-shot zero init
  const size_t PKE = (size_t)5 * 32 * 8 * 512;
  const size_t PKD = (size_t)7 * 32 * 8 * 512;
  u16* hEpkH = allocu(PKE);
  u16* hEpkL = allocu(PKE);
  u16* uEpkH = allocu(PKE);
  u16* uEpkL = allocu(PKE);
  u16* hDpkH = allocu(PKD);
  u16* hDpkL = allocu(PKD);
  u16* uDpkH = allocu(PKD);
  u16* uDpkL = allocu(PKD);
  const size_t PKTOT = 4 * PKE + 4 * PKD;

  // ---- PRNG keys (jax partitionable threefry) ----
  uint32_t ka0, ka1, kb0, kb1;
  tf2x32(0u, 42u, 0u, 0u, &ka0, &ka1);
  tf2x32(0u, 42u, 0u, 1u, &kb0, &kb1);

  // ---- init + graph setup ----
  zero_kernel<<<1024, 256, 0, stream>>>((uint4*)hEpkH, (int)(PKTOT / 8));
  setup_embed_kernel<<<1, 256, 0, stream>>>(We1, We2, Mem, e1, e2, n1, n2);
  stats_init_kernel<<<1, 1, 0, stream>>>(stats);
  adj_kernel<<<256, 256, 0, stream>>>(e1, e2, n1, n2, ka0, ka1, adj, deg, stats);
  lap_kernel<<<256, 256, 0, stream>>>(adj, deg, stats, Sf);
  t2_kernel<<<dim3(4, 4), 256, 0, stream>>>(Sf, Sf + 65536);
  stats_init_kernel<<<1, 1, 0, stream>>>(stats);
  adj_kernel<<<256, 256, 0, stream>>>(e2, e1, n2, n1, kb0, kb1, adj, deg, stats);
  lap_kernel<<<256, 256, 0, stream>>>(adj, deg, stats, Sf + 2 * 65536);
  t2_kernel<<<dim3(4, 4), 256, 0, stream>>>(Sf + 2 * 65536, Sf + 3 * 65536);
  cvt_s_packed<<<1024, 256, 0, stream>>>(Sf, SpkH, SpkL);
  build_wfrag<<<(5 * 64 * 128 + 255) / 256, 256, 0, stream>>>(egw, 65, 128, 64, WgEh, WgEl, w0gE, wlgE);
  build_wfrag<<<(5 * 64 * 64 + 255) / 256, 256, 0, stream>>>(euw, 65, 64, 64, WuEh, WuEl, w0uE, wluE);
  build_wfrag<<<(5 * 96 * 192 + 255) / 256, 256, 0, stream>>>(dgw, 97, 192, 96, WgDh, WgDl, w0gD, wlgD);
  build_wfrag<<<(5 * 96 * 96 + 255) / 256, 256, 0, stream>>>(duw, 97, 96, 96, WuDh, WuDl, w0uD, wluD);

  // ---- encoder ----
  enc_init<<<32, 256, 0, stream>>>(x, hEpkH, hEpkL);
  for (int t = 0; t < TLEN; ++t) {
    fused_step<65, 64, 128, 2, 5, 0><<<512, 1024, 0, stream>>>(
        hEpkH, hEpkL, SpkH, SpkL, WgEh, WgEl, w0gE, wlgE, egb,
        hEpkH, hEpkL, uEpkH, uEpkL, rb, nullptr, -1, nullptr, nullptr, nullptr, 0);
    fused_step<65, 64, 64, 2, 5, 1><<<512, 1024, 0, stream>>>(
        uEpkH, uEpkL, SpkH, SpkL, WuEh, WuEl, w0uE, wluE, eub,
        hEpkH, hEpkL, hEpkH, hEpkL, rb,
        x, (t + 1 < TLEN) ? (t + 1) : -1, nullptr, nullptr, nullptr, 0);
  }

  // ---- attention + decoder init ----
  attn2<<<64, 128, 0, stream>>>(hEpkH, hEpkL, Wq, Mem, hDpkH, hDpkL);

  // ---- decoder ----
  for (int t = 0; t < TLEN; ++t) {
    fused_step<97, 96, 192, 3, 7, 0><<<512, 1024, 0, stream>>>(
        hDpkH, hDpkL, SpkH, SpkL, WgDh, WgDl, w0gD, wlgD, dgb,
        hDpkH, hDpkL, uDpkH, uDpkL, rb, nullptr, -1, nullptr, nullptr, nullptr, 0);
    fused_step<97, 96, 96, 3, 7, 2><<<512, 1024, 0, stream>>>(
        uDpkH, uDpkL, SpkH, SpkL, WuDh, WuDl, w0uD, wluD, dub,
        hDpkH, hDpkL, hDpkH, hDpkL, rb,
        nullptr, -1, pw, pb, out, t);
  }
}

// Round 16
// 7999.525 us; speedup vs baseline: 2.7123x; 1.1509x over previous
//
#include <hip/hip_runtime.h>
#include <stdint.h>
#include <math.h>

// ====================== problem constants ======================
#define NNODE 256
#define BATCH 32
#define TLEN  128
#define ROWS  8192 // NNODE*BATCH

typedef unsigned short u16;
typedef short bf16x8 __attribute__((ext_vector_type(8)));
typedef float f32x4 __attribute__((ext_vector_type(4)));

__device__ inline u16 f2bf_rn(float v) {
  uint32_t u = __float_as_uint(v);
  u += 0x7fffu + ((u >> 16) & 1u);
  return (u16)(u >> 16);
}
__device__ inline float bf2f(u16 h) { return __uint_as_float(((uint32_t)h) << 16); }
__device__ inline void split2(float v, u16& hi, u16& lo) {
  hi = f2bf_rn(v);
  lo = f2bf_rn(v - bf2f(hi));
}

// packed-state element address: fragment (ct=c/16, b, mc=n/32), lane-major
__device__ inline size_t pk_addr(int c, int b, int n) {
  return ((((size_t)(c >> 4) * 32 + b) * 8 + (n >> 5)) << 9) +
         (((size_t)((c & 15) | (((n >> 3) & 3) << 4))) << 3) + (n & 7);
}

// ====================== Threefry-2x32 (20 rounds) ======================
__host__ __device__ inline uint32_t rotl32_(uint32_t v, int d) {
  return (v << d) | (v >> (32 - d));
}
__host__ __device__ inline void tf2x32(uint32_t k0, uint32_t k1, uint32_t x0,
                                       uint32_t x1, uint32_t* o0, uint32_t* o1) {
  uint32_t ks2 = k0 ^ k1 ^ 0x1BD11BDAu;
  x0 += k0; x1 += k1;
  x0 += x1; x1 = rotl32_(x1, 13); x1 ^= x0;
  x0 += x1; x1 = rotl32_(x1, 15); x1 ^= x0;
  x0 += x1; x1 = rotl32_(x1, 26); x1 ^= x0;
  x0 += x1; x1 = rotl32_(x1, 6);  x1 ^= x0;
  x0 += k1; x1 += ks2 + 1u;
  x0 += x1; x1 = rotl32_(x1, 17); x1 ^= x0;
  x0 += x1; x1 = rotl32_(x1, 29); x1 ^= x0;
  x0 += x1; x1 = rotl32_(x1, 16); x1 ^= x0;
  x0 += x1; x1 = rotl32_(x1, 24); x1 ^= x0;
  x0 += ks2; x1 += k0 + 2u;
  x0 += x1; x1 = rotl32_(x1, 13); x1 ^= x0;
  x0 += x1; x1 = rotl32_(x1, 15); x1 ^= x0;
  x0 += x1; x1 = rotl32_(x1, 26); x1 ^= x0;
  x0 += x1; x1 = rotl32_(x1, 6);  x1 ^= x0;
  x0 += k0; x1 += k1 + 3u;
  x0 += x1; x1 = rotl32_(x1, 17); x1 ^= x0;
  x0 += x1; x1 = rotl32_(x1, 29); x1 ^= x0;
  x0 += x1; x1 = rotl32_(x1, 16); x1 ^= x0;
  x0 += x1; x1 = rotl32_(x1, 24); x1 ^= x0;
  x0 += k1; x1 += ks2 + 4u;
  x0 += x1; x1 = rotl32_(x1, 13); x1 ^= x0;
  x0 += x1; x1 = rotl32_(x1, 15); x1 ^= x0;
  x0 += x1; x1 = rotl32_(x1, 26); x1 ^= x0;
  x0 += x1; x1 = rotl32_(x1, 6);  x1 ^= x0;
  x0 += ks2; x1 += k0 + 5u;
  *o0 = x0; *o1 = x1;
}

__device__ inline float gumbel_at(uint32_t k0, uint32_t k1, uint32_t idx) {
  uint32_t o0, o1;
  tf2x32(k0, k1, 0u, idx, &o0, &o1);
  uint32_t b = o0 ^ o1;
  float f = __uint_as_float((b >> 9) | 0x3f800000u) - 1.0f;
  const float tiny = 1.17549435e-38f;
  float u = fmaxf(tiny, f + tiny);
  return -logf(-logf(u));
}

// ====================== graph setup kernels (fp32, one-time) ======================
__global__ __launch_bounds__(256) void setup_embed_kernel(
    const float* __restrict__ We1, const float* __restrict__ We2,
    const float* __restrict__ Mem, float* __restrict__ e1, float* __restrict__ e2,
    float* __restrict__ n1, float* __restrict__ n2) {
  int n = threadIdx.x;
  float a[8];
  float s;
  for (int m = 0; m < 8; ++m) a[m] = We1[n * 8 + m];
  s = 0.f;
  for (int j = 0; j < 32; ++j) {
    float v = 0.f;
    for (int m = 0; m < 8; ++m) v = fmaf(a[m], Mem[m * 32 + j], v);
    e1[n * 32 + j] = v;
    s = fmaf(v, v, s);
  }
  n1[n] = sqrtf(s);
  for (int m = 0; m < 8; ++m) a[m] = We2[n * 8 + m];
  s = 0.f;
  for (int j = 0; j < 32; ++j) {
    float v = 0.f;
    for (int m = 0; m < 8; ++m) v = fmaf(a[m], Mem[m * 32 + j], v);
    e2[n * 32 + j] = v;
    s = fmaf(v, v, s);
  }
  n2[n] = sqrtf(s);
}

__global__ void stats_init_kernel(int* stats) {
  stats[0] = 0;
  stats[1] = 0;
  stats[2] = 0x7fffffff;
}

__global__ __launch_bounds__(256) void adj_kernel(
    const float* __restrict__ eA, const float* __restrict__ eB,
    const float* __restrict__ nA, const float* __restrict__ nB,
    uint32_t k0, uint32_t k1, float* __restrict__ adj, float* __restrict__ deg,
    int* __restrict__ stats) {
  int i = blockIdx.x, j = threadIdx.x;
  float dot = 0.f;
  for (int c = 0; c < 32; ++c) dot = fmaf(eA[i * 32 + c], eB[j * 32 + c], dot);
  float g = dot / (nA[i] * nB[j] + 1e-6f);
  g = (g + 1.0f) * 0.5f;
  uint32_t f = ((uint32_t)(i * 256 + j)) * 2u;
  float g0 = gumbel_at(k0, k1, f);
  float g1 = gumbel_at(k0, k1, f + 1u);
  float a = ((g + g0) >= ((1.0f - g) + g1)) ? 1.0f : 0.0f;
  if (i == j) a = 0.0f;
  adj[i * 256 + j] = a;
  __shared__ float red[256];
  red[j] = a;
  __syncthreads();
  for (int s = 128; s > 0; s >>= 1) {
    if (j < s) red[j] += red[j + s];
    __syncthreads();
  }
  if (j == 0) {
    float d = red[0];
    deg[i] = d;
    atomicMax(&stats[0], (int)d);
    atomicMin(&stats[2], (int)d);
    if (d > 0.5f) atomicOr(&stats[1], 1);
  }
}

__global__ __launch_bounds__(256) void lap_kernel(const float* __restrict__ adj,
                                                  const float* __restrict__ deg,
                                                  const int* __restrict__ stats,
                                                  float* __restrict__ S1) {
  int i = blockIdx.x, j = threadIdx.x;
  float lmax = (float)stats[0];
  float lmin = stats[1] ? -1.0f : (float)stats[2];
  float lam = lmax - lmin;
  float L = (i == j) ? deg[i] : -adj[i * 256 + j];
  S1[i * 256 + j] = 2.0f * L / lam - ((i == j) ? 1.0f : 0.0f);
}

// T2 = 2*(S1@S1) - I  (fp32 VALU tile GEMM, one-time)
__global__ __launch_bounds__(256) void t2_kernel(const float* __restrict__ A,
                                                 float* __restrict__ Cout) {
  __shared__ __align__(16) float sAT[32][68];
  __shared__ __align__(16) float sB[32][68];
  int tid = threadIdx.x;
  int tc = tid & 15, tr = tid >> 4;
  int row0 = blockIdx.y * 64, col0 = blockIdx.x * 64;
  float acc[4][4] = {};
  for (int m0 = 0; m0 < 256; m0 += 32) {
    for (int i = tid; i < 2048; i += 256) {
      int r = i >> 5, c = i & 31;
      sAT[c][r] = A[(size_t)(row0 + r) * 256 + m0 + c];
    }
    for (int i = tid; i < 2048; i += 256) {
      int r = i >> 6, c = i & 63;
      sB[r][c] = A[(size_t)(m0 + r) * 256 + col0 + c];
    }
    __syncthreads();
#pragma unroll
    for (int kk = 0; kk < 32; ++kk) {
      float4 av = *(const float4*)&sAT[kk][tr * 4];
      float4 bv = *(const float4*)&sB[kk][tc * 4];
      float a[4] = {av.x, av.y, av.z, av.w};
      float b[4] = {bv.x, bv.y, bv.z, bv.w};
#pragma unroll
      for (int i = 0; i < 4; ++i)
#pragma unroll
        for (int j = 0; j < 4; ++j) acc[i][j] = fmaf(a[i], b[j], acc[i][j]);
    }
    __syncthreads();
  }
#pragma unroll
  for (int i = 0; i < 4; ++i) {
    int row = row0 + tr * 4 + i;
#pragma unroll
    for (int j = 0; j < 4; ++j) {
      int col = col0 + tc * 4 + j;
      Cout[(size_t)row * 256 + col] = 2.0f * acc[i][j] - ((row == col) ? 1.0f : 0.0f);
    }
  }
}

// S fp32 -> fragment-packed hi/lo bf16
__global__ void cvt_s_packed(const float* __restrict__ S, u16* __restrict__ Sh,
                             u16* __restrict__ Sl) {
  int idx = blockIdx.x * 256 + threadIdx.x;
  if (idx >= 4 * 65536) return;
  int p = idx >> 16, rem = idx & 65535;
  int n = rem >> 8, m = rem & 255;
  int nt = n >> 4, li = n & 15;
  int mc = m >> 5, g = (m >> 3) & 3, j = m & 7;
  int lane = li | (g << 4);
  size_t a = (((size_t)(p * 16 + nt) * 8 + mc) << 9) + lane * 8 + j;
  u16 h, l;
  split2(S[idx], h, l);
  Sh[a] = h; Sl[a] = l;
}

// W fragment-packed (k=3 folded into p=0; c==0/c==hid via rank-1 w0/wlast)
__global__ void build_wfrag(const float* __restrict__ W, int C, int O, int hid,
                            u16* __restrict__ WfH, u16* __restrict__ WfL,
                            float* __restrict__ w0, float* __restrict__ wlast) {
  int idx = blockIdx.x * 256 + threadIdx.x;
  int nKC = hid / 32;
  if (idx < 5 * hid * O) {
    int kk = idx & 31;
    int rest = idx >> 5;
    int o = rest % O; rest /= O;
    int kc = rest % nKC;
    int p = rest / nKC;
    int korig = (p == 0) ? 0 : (p + (p >= 3 ? 1 : 0));
    int c = kc * 32 + kk;
    float v = 0.f;
    if (c > 0) {
      v = W[(size_t)(korig * C + c) * O + o];
      if (p == 0) v += W[(size_t)(3 * C + c) * O + o];
    }
    int ot = o >> 4, li = o & 15, g = kk >> 3, j = kk & 7;
    int lane = li | (g << 4);
    size_t a = (((size_t)(p * nKC + kc) * (O / 16) + ot) << 9) + lane * 8 + j;
    u16 h, l; split2(v, h, l);
    WfH[a] = h; WfL[a] = l;
  }
  if (idx < 5 * O) {
    int o = idx % O, p = idx / O;
    int korig = (p == 0) ? 0 : (p + (p >= 3 ? 1 : 0));
    float v0 = W[(size_t)(korig * C + 0) * O + o];
    if (p == 0) v0 += W[(size_t)(3 * C + 0) * O + o];
    w0[p * O + o] = v0;
    float vl = W[(size_t)(korig * C + hid) * O + o];
    if (p == 0) vl += W[(size_t)(3 * C + hid) * O + o];
    wlast[p * O + o] = vl;
  }
}

__global__ void zero_kernel(uint4* __restrict__ p, int n4) {
  for (int i = blockIdx.x * blockDim.x + threadIdx.x; i < n4;
       i += gridDim.x * blockDim.x)
    p[i] = make_uint4(0, 0, 0, 0);
}

// encoder state init: packed ch0 = x[:,0] (rest already zeroed)
__global__ void enc_init(const float* __restrict__ x,
                         u16* __restrict__ pkh, u16* __restrict__ pkl) {
  int col = blockIdx.x * 256 + threadIdx.x;
  if (col >= ROWS) return;
  int b = col >> 8, n = col & 255;
  float v = x[(size_t)b * (TLEN * NNODE) + n];
  u16 h, l; split2(v, h, l);
  size_t a = pk_addr(0, b, n);
  pkh[a] = h; pkl[a] = l;
}

// attention + decoder state init (packed only)
__global__ __launch_bounds__(128) void attn2(const u16* __restrict__ hEh,
                                             const u16* __restrict__ hEl,
                                             const float* __restrict__ Wq,
                                             const float* __restrict__ Mem,
                                             u16* __restrict__ pkh,
                                             u16* __restrict__ pkl) {
  int col = blockIdx.x * 128 + threadIdx.x;
  int b = col >> 8, n = col & 255;
  float h[64];
  for (int c = 0; c < 64; ++c) {
    size_t a = pk_addr(1 + c, b, n);
    h[c] = bf2f(hEh[a]) + bf2f(hEl[a]);
  }
  float q[32];
  for (int j = 0; j < 32; ++j) {
    float s = 0.f;
    for (int c = 0; c < 64; ++c) s = fmaf(h[c], Wq[c * 32 + j], s);
    q[j] = s;
  }
  float l[8], mx = -3.402823466e38f;
  for (int m = 0; m < 8; ++m) {
    float s = 0.f;
    for (int j = 0; j < 32; ++j) s = fmaf(q[j], Mem[m * 32 + j], s);
    l[m] = s;
    mx = fmaxf(mx, s);
  }
  float se = 0.f;
  for (int m = 0; m < 8; ++m) { l[m] = expf(l[m] - mx); se += l[m]; }
  float val[32];
  for (int j = 0; j < 32; ++j) {
    float v = 0.f;
    for (int m = 0; m < 8; ++m) v = fmaf(l[m] / se, Mem[m * 32 + j], v);
    val[j] = v;
  }
  for (int c = 0; c < 97; ++c) {
    float v = (c == 0) ? 0.f : ((c <= 64) ? h[c - 1] : val[c - 65]);
    u16 hh, ll; split2(v, hh, ll);
    size_t a = pk_addr(c, b, n);
    pkh[a] = hh; pkl[a] = ll;
  }
}

// ====================== fused half-step kernel ======================
// R10 structure (per-launch, direct loads, no GEMM1 barriers) +
//  - G LDS layout [slot/8][li][8]: GEMM2 ds_read_b128 2-way (free) vs 8-way
//  - all state packed-only (f32 buffers eliminated): G0 fill is a raw copy
//    (bit-identical); hp/z*h/ch0/attn use hi+lo reconstruction (2^-17 class).
// Block: 32 cols, 1024 thr (16 waves), grid 256 XCD-swizzled.
// GEMM1: wave = (cg, S-piece pp, half of c-tiles). GEMM2: wave = O-tile.
template <int C, int HID, int O, int NKC, int MT1, int MODE>
__global__ __launch_bounds__(1024, 4) void fused_step(
    const u16* __restrict__ ApkH, const u16* __restrict__ ApkL,
    const u16* __restrict__ SpkH, const u16* __restrict__ SpkL,
    const u16* __restrict__ WpkH, const u16* __restrict__ WpkL,
    const float* __restrict__ w0, const float* __restrict__ wlast,
    const float* __restrict__ bias,
    const u16* __restrict__ stH, const u16* __restrict__ stL,
    u16* __restrict__ outPkH, u16* __restrict__ outPkL,
    float* __restrict__ rbuf,
    const float* __restrict__ xsrc, int tnext,
    const float* __restrict__ pw, const float* __restrict__ pb,
    float* __restrict__ outp, int tcur) {
  constexpr int MT2 = O / 16;
  constexpr int MT1A = (MT1 + 1) / 2;
  constexpr int CH0SLOT = HID + 1;
  constexpr int KS8 = (HID + 9) / 8;

  __shared__ __align__(16) u16 GhR[(size_t)2 * 5 * KS8 * 16 * 8];
  __shared__ __align__(16) u16 GlR[(size_t)2 * 5 * KS8 * 16 * 8];
  __shared__ float projL[(MODE == 2) ? 32 * 100 : 4];

  auto Gidx = [](int c2, int p, int li, int slot) -> size_t {
    return (((size_t)((c2 * 5 + p) * KS8 + (slot >> 3)) * 16 + li) << 3) +
           (slot & 7);
  };

  const int tid = threadIdx.x;
  const int wid = tid >> 6, lane = tid & 63;
  const int g = lane >> 4, li = lane & 15;
  const int cgi = wid >> 3, pp = wid & 3, half = (wid >> 2) & 1;
  const int bid0 = (int)blockIdx.x;
  const int bidx = ((bid0 & 7) << 5) | (bid0 >> 3);
  const int col0 = bidx * 32;
  const int b = col0 >> 8;
  const int nb = col0 & 255;  // n-base of the 32 columns
  const int n0 = nb + cgi * 16;
  const int nt = n0 >> 4;

  // ---- stage G_0: raw copy of packed state (bit-identical to f32 split) ----
  for (int i = tid; i < 32 * C; i += 1024) {
    int c = i >> 5, q = i & 31;
    size_t a = pk_addr(c, b, nb + q);
    int slot = (c == 0) ? CH0SLOT : c;
    GhR[Gidx(q >> 4, 0, q & 15, slot)] = ApkH[a];
    GlR[Gidx(q >> 4, 0, q & 15, slot)] = ApkL[a];
  }
  if (tid < 32) {
    GhR[Gidx(tid >> 4, 0, tid & 15, 0)] = 0;
    GlR[Gidx(tid >> 4, 0, tid & 15, 0)] = 0;
  }

  // ---- GEMM1: wave owns (cg, S-piece pp, half of c-tiles); direct loads ----
  f32x4 acc1[MT1A];
#pragma unroll
  for (int i = 0; i < MT1A; ++i) acc1[i] = (f32x4){0.f, 0.f, 0.f, 0.f};

#pragma unroll 2
  for (int mc = 0; mc < 8; ++mc) {
    size_t sa = (((size_t)(pp * 16 + nt) * 8 + mc) << 9) + lane * 8;
    bf16x8 sbh = *(const bf16x8*)(SpkH + sa);
    bf16x8 sbl = *(const bf16x8*)(SpkL + sa);
#pragma unroll
    for (int i = 0; i < MT1A; ++i) {
      const int mt = half * MT1A + i;
      if (mt < MT1) {
        size_t aa = (((size_t)(mt * 32 + b) * 8 + mc) << 9) + lane * 8;
        bf16x8 ah = *(const bf16x8*)(ApkH + aa);
        bf16x8 al = *(const bf16x8*)(ApkL + aa);
        acc1[i] = __builtin_amdgcn_mfma_f32_16x16x32_bf16(ah, sbh, acc1[i], 0, 0, 0);
        acc1[i] = __builtin_amdgcn_mfma_f32_16x16x32_bf16(ah, sbl, acc1[i], 0, 0, 0);
        acc1[i] = __builtin_amdgcn_mfma_f32_16x16x32_bf16(al, sbh, acc1[i], 0, 0, 0);
      }
    }
  }

  // ---- epi1: split + write G_{pp+1} to LDS ----
  {
    const int p = pp + 1;
#pragma unroll
    for (int i = 0; i < MT1A; ++i) {
      const int mt = half * MT1A + i;
      if (mt < MT1) {
        int cq = mt * 16 + 4 * g;
        u16 h4[4], l4[4];
#pragma unroll
        for (int r = 0; r < 4; ++r) split2(acc1[i][r], h4[r], l4[r]);
        if (cq == 0) {
          GhR[Gidx(cgi, p, li, CH0SLOT)] = h4[0];
          GlR[Gidx(cgi, p, li, CH0SLOT)] = l4[0];
          h4[0] = 0; l4[0] = 0;
        }
        if (cq + 3 <= HID) {
          uint2 vh, vl;
          vh.x = (uint32_t)h4[0] | ((uint32_t)h4[1] << 16);
          vh.y = (uint32_t)h4[2] | ((uint32_t)h4[3] << 16);
          vl.x = (uint32_t)l4[0] | ((uint32_t)l4[1] << 16);
          vl.y = (uint32_t)l4[2] | ((uint32_t)l4[3] << 16);
          *(uint2*)&GhR[Gidx(cgi, p, li, cq)] = vh;
          *(uint2*)&GlR[Gidx(cgi, p, li, cq)] = vl;
        } else {
#pragma unroll
          for (int r = 0; r < 4; ++r) {
            int c = cq + r;
            if (c >= 1 && c <= HID) {
              GhR[Gidx(cgi, p, li, c)] = h4[r];
              GlR[Gidx(cgi, p, li, c)] = l4[r];
            }
          }
        }
      }
    }
  }
  __syncthreads();

  // ---- GEMM2: wave = one O-tile, both col-groups; W 1x/block ----
  const int mt2 = wid;
  f32x4 acc2[2];
  acc2[0] = (f32x4){0.f, 0.f, 0.f, 0.f};
  acc2[1] = (f32x4){0.f, 0.f, 0.f, 0.f};
  if (mt2 < MT2) {
#pragma unroll
    for (int p = 0; p < 5; ++p) {
#pragma unroll
      for (int kc = 0; kc < NKC; ++kc) {
        bf16x8 bh[2], bl[2];
#pragma unroll
        for (int c2 = 0; c2 < 2; ++c2) {
          bh[c2] = *(const bf16x8*)&GhR[Gidx(c2, p, li, kc * 32 + g * 8)];
          bl[c2] = *(const bf16x8*)&GlR[Gidx(c2, p, li, kc * 32 + g * 8)];
        }
        size_t wa = (((size_t)(p * NKC + kc) * MT2 + mt2) << 9) + lane * 8;
        bf16x8 wh = *(const bf16x8*)(WpkH + wa);
        bf16x8 wl = *(const bf16x8*)(WpkL + wa);
#pragma unroll
        for (int c2 = 0; c2 < 2; ++c2) {
          acc2[c2] = __builtin_amdgcn_mfma_f32_16x16x32_bf16(wh, bh[c2], acc2[c2], 0, 0, 0);
          acc2[c2] = __builtin_amdgcn_mfma_f32_16x16x32_bf16(wh, bl[c2], acc2[c2], 0, 0, 0);
          acc2[c2] = __builtin_amdgcn_mfma_f32_16x16x32_bf16(wl, bh[c2], acc2[c2], 0, 0, 0);
        }
      }
    }
  }

  // ---- rank-1 inputs (c=0 and c=HID), both col-groups ----
  float ch0v[2][5], clv[2][5];
#pragma unroll
  for (int c2 = 0; c2 < 2; ++c2)
#pragma unroll
    for (int p = 0; p < 5; ++p) {
      if (p == 0) {
        size_t a = pk_addr(0, b, nb + c2 * 16 + li);
        ch0v[c2][p] = bf2f(ApkH[a]) + bf2f(ApkL[a]);
      } else {
        ch0v[c2][p] = bf2f(GhR[Gidx(c2, p, li, CH0SLOT)]) +
                      bf2f(GlR[Gidx(c2, p, li, CH0SLOT)]);
      }
      clv[c2][p] = bf2f(GhR[Gidx(c2, p, li, HID)]) + bf2f(GlR[Gidx(c2, p, li, HID)]);
    }

  // ---- epilogue ----
  if (mt2 < MT2) {
#pragma unroll
    for (int c2 = 0; c2 < 2; ++c2) {
      const int ncolx = nb + c2 * 16 + li;
      const int colx = col0 + c2 * 16 + li;
#pragma unroll
      for (int r = 0; r < 4; ++r) {
        int o = mt2 * 16 + 4 * g + r;
        float v = acc2[c2][r] + bias[o];
#pragma unroll
        for (int p = 0; p < 5; ++p) {
          v = fmaf(w0[p * O + o], ch0v[c2][p], v);
          v = fmaf(wlast[p * O + o], clv[c2][p], v);
        }
        size_t a = pk_addr(1 + o, b, ncolx);
        if (MODE == 0) {
          float s = 1.0f / (1.0f + expf(-v));
          if (o < HID) {
            float hrec = bf2f(stH[a]) + bf2f(stL[a]);
            float u = s * hrec;
            u16 h_, l_; split2(u, h_, l_);
            outPkH[a] = h_; outPkL[a] = l_;
          } else {
            rbuf[(size_t)(o - HID) * ROWS + colx] = s;
          }
        } else {
          float hc = tanhf(v);
          float hp = bf2f(stH[a]) + bf2f(stL[a]);
          float rr = rbuf[(size_t)o * ROWS + colx];
          float hn = rr * hp + (1.0f - rr) * hc;
          u16 h_, l_; split2(hn, h_, l_);
          outPkH[a] = h_; outPkL[a] = l_;
          if (MODE == 2) projL[((size_t)c2 * 16 + li) * 100 + o] = hn;
        }
      }
    }
  }

  if (MODE == 0) {
    // u ch0 = input ch0 (raw packed copy — bit-identical)
    if (tid < 32) {
      size_t a = pk_addr(0, b, nb + tid);
      outPkH[a] = ApkH[a];
      outPkL[a] = ApkL[a];
    }
  }
  if (MODE == 1) {
    if (tnext >= 0 && tid < 32) {
      int n = nb + tid;
      float xv = xsrc[(size_t)b * (TLEN * NNODE) + (size_t)tnext * NNODE + n];
      u16 h_, l_; split2(xv, h_, l_);
      size_t a = pk_addr(0, b, n);
      outPkH[a] = h_; outPkL[a] = l_;
    }
    // tnext<0: keep existing ch0 (no write needed)
  }
  if (MODE == 2) {
    __syncthreads();  // projL complete
    if (tid < 32) {
      int n = nb + tid;
      float s = pb[0];
#pragma unroll
      for (int o = 0; o < HID; ++o) s = fmaf(pw[o], projL[(size_t)tid * 100 + o], s);
      u16 h_, l_; split2(s, h_, l_);
      size_t a = pk_addr(0, b, n);
      outPkH[a] = h_; outPkL[a] = l_;
      outp[((size_t)b * TLEN + tcur) * NNODE + n] = s;
    }
  }
}

// ====================== host launch ======================
extern "C" void kernel_launch(void* const* d_in, const int* in_sizes, int n_in,
                              void* d_out, int out_size, void* d_ws, size_t ws_size,
                              hipStream_t stream) {
  (void)in_sizes; (void)n_in; (void)out_size; (void)ws_size;
  const float* x   = (const float*)d_in[0];
  const float* Mem = (const float*)d_in[1];
  const float* Wq  = (const float*)d_in[2];
  const float* We1 = (const float*)d_in[3];
  const float* We2 = (const float*)d_in[4];
  const float* egw = (const float*)d_in[5];
  const float* egb = (const float*)d_in[6];
  const float* euw = (const float*)d_in[7];
  const float* eub = (const float*)d_in[8];
  const float* dgw = (const float*)d_in[9];
  const float* dgb = (const float*)d_in[10];
  const float* duw = (const float*)d_in[11];
  const float* dub = (const float*)d_in[12];
  const float* pw  = (const float*)d_in[13];
  const float* pb  = (const float*)d_in[14];
  float* out = (float*)d_out;

  float* ws = (float*)d_ws;
  size_t off = 0;
  auto allocf = [&](size_t nf) {
    float* p = ws + off;
    off += (nf + 63) & ~(size_t)63;
    return p;
  };
  auto allocu = [&](size_t nu) { return (u16*)allocf((nu + 1) / 2); };

  float* Sf  = allocf(4 * 65536);
  float* e1  = allocf(8192);
  float* e2  = allocf(8192);
  float* n1  = allocf(256);
  float* n2  = allocf(256);
  float* adj = allocf(65536);
  float* deg = allocf(256);
  int* stats = (int*)allocf(64);
  float* rb  = allocf((size_t)96 * ROWS);
  float* w0gE = allocf(5 * 128);
  float* w0uE = allocf(5 * 64);
  float* w0gD = allocf(5 * 192);
  float* w0uD = allocf(5 * 96);
  float* wlgE = allocf(5 * 128);
  float* wluE = allocf(5 * 64);
  float* wlgD = allocf(5 * 192);
  float* wluD = allocf(5 * 96);

  u16* SpkH = allocu((size_t)4 * 65536);
  u16* SpkL = allocu((size_t)4 * 65536);
  u16* WgEh = allocu((size_t)5 * 2 * 8 * 512);
  u16* WgEl = allocu((size_t)5 * 2 * 8 * 512);
  u16* WuEh = allocu((size_t)5 * 2 * 4 * 512);
  u16* WuEl = allocu((size_t)5 * 2 * 4 * 512);
  u16* WgDh = allocu((size_t)5 * 3 * 12 * 512);
  u16* WgDl = allocu((size_t)5 * 3 * 12 * 512);
  u16* WuDh = allocu((size_t)5 * 3 * 6 * 512);
  u16* WuDl = allocu((size_t)5 * 3 * 6 * 512);

  // packed states — contiguous for one-shot zero init
  const size_t PKE = (size_t)5 * 32 * 8 * 512;
  const size_t PKD = (size_t)7 * 32 * 8 * 512;
  u16* hEpkH = allocu(PKE);
  u16* hEpkL = allocu(PKE);
  u16* uEpkH = allocu(PKE);
  u16* uEpkL = allocu(PKE);
  u16* hDpkH = allocu(PKD);
  u16* hDpkL = allocu(PKD);
  u16* uDpkH = allocu(PKD);
  u16* uDpkL = allocu(PKD);
  const size_t PKTOT = 4 * PKE + 4 * PKD;

  // ---- PRNG keys (jax partitionable threefry) ----
  uint32_t ka0, ka1, kb0, kb1;
  tf2x32(0u, 42u, 0u, 0u, &ka0, &ka1);
  tf2x32(0u, 42u, 0u, 1u, &kb0, &kb1);

  // ---- init + graph setup ----
  zero_kernel<<<1024, 256, 0, stream>>>((uint4*)hEpkH, (int)(PKTOT / 8));
  setup_embed_kernel<<<1, 256, 0, stream>>>(We1, We2, Mem, e1, e2, n1, n2);
  stats_init_kernel<<<1, 1, 0, stream>>>(stats);
  adj_kernel<<<256, 256, 0, stream>>>(e1, e2, n1, n2, ka0, ka1, adj, deg, stats);
  lap_kernel<<<256, 256, 0, stream>>>(adj, deg, stats, Sf);
  t2_kernel<<<dim3(4, 4), 256, 0, stream>>>(Sf, Sf + 65536);
  stats_init_kernel<<<1, 1, 0, stream>>>(stats);
  adj_kernel<<<256, 256, 0, stream>>>(e2, e1, n2, n1, kb0, kb1, adj, deg, stats);
  lap_kernel<<<256, 256, 0, stream>>>(adj, deg, stats, Sf + 2 * 65536);
  t2_kernel<<<dim3(4, 4), 256, 0, stream>>>(Sf + 2 * 65536, Sf + 3 * 65536);
  cvt_s_packed<<<1024, 256, 0, stream>>>(Sf, SpkH, SpkL);
  build_wfrag<<<(5 * 64 * 128 + 255) / 256, 256, 0, stream>>>(egw, 65, 128, 64, WgEh, WgEl, w0gE, wlgE);
  build_wfrag<<<(5 * 64 * 64 + 255) / 256, 256, 0, stream>>>(euw, 65, 64, 64, WuEh, WuEl, w0uE, wluE);
  build_wfrag<<<(5 * 96 * 192 + 255) / 256, 256, 0, stream>>>(dgw, 97, 192, 96, WgDh, WgDl, w0gD, wlgD);
  build_wfrag<<<(5 * 96 * 96 + 255) / 256, 256, 0, stream>>>(duw, 97, 96, 96, WuDh, WuDl, w0uD, wluD);

  // ---- encoder ----
  enc_init<<<32, 256, 0, stream>>>(x, hEpkH, hEpkL);
  for (int t = 0; t < TLEN; ++t) {
    fused_step<65, 64, 128, 2, 5, 0><<<256, 1024, 0, stream>>>(
        hEpkH, hEpkL, SpkH, SpkL, WgEh, WgEl, w0gE, wlgE, egb,
        hEpkH, hEpkL, uEpkH, uEpkL, rb, nullptr, -1, nullptr, nullptr, nullptr, 0);
    fused_step<65, 64, 64, 2, 5, 1><<<256, 1024, 0, stream>>>(
        uEpkH, uEpkL, SpkH, SpkL, WuEh, WuEl, w0uE, wluE, eub,
        hEpkH, hEpkL, hEpkH, hEpkL, rb,
        x, (t + 1 < TLEN) ? (t + 1) : -1, nullptr, nullptr, nullptr, 0);
  }

  // ---- attention + decoder init ----
  attn2<<<64, 128, 0, stream>>>(hEpkH, hEpkL, Wq, Mem, hDpkH, hDpkL);

  // ---- decoder ----
  for (int t = 0; t < TLEN; ++t) {
    fused_step<97, 96, 192, 3, 7, 0><<<256, 1024, 0, stream>>>(
        hDpkH, hDpkL, SpkH, SpkL, WgDh, WgDl, w0gD, wlgD, dgb,
        hDpkH, hDpkL, uDpkH, uDpkL, rb, nullptr, -1, nullptr, nullptr, nullptr, 0);
    fused_step<97, 96, 96, 3, 7, 2><<<256, 1024, 0, stream>>>(
        uDpkH, uDpkL, SpkH, SpkL, WuDh, WuDl, w0uD, wluD, dub,
        hDpkH, hDpkL, hDpkH, hDpkL, rb,
        nullptr, -1, pw, pb, out, t);
  }
}